// Round 9
// baseline (51009.610 us; speedup 1.0000x reference)
//
#include <hip/hip_runtime.h>
#include <cstdint>

typedef unsigned short ushortT;
typedef __attribute__((ext_vector_type(8))) short s8v;   // 8 bf16 (4 VGPRs)
typedef __attribute__((ext_vector_type(4))) float f4v;   // MFMA acc

#define TIN 400
#define TOUT 500

// ---------------- threefry2x32 (JAX, 20 rounds) ----------------
__host__ __device__ __forceinline__ uint32_t rotl32(uint32_t v, int r){ return (v<<r)|(v>>(32-r)); }
__host__ __device__ inline void tf2x32(uint32_t k0, uint32_t k1, uint32_t x0, uint32_t x1,
                                       uint32_t* o0, uint32_t* o1){
  uint32_t ks2 = k0 ^ k1 ^ 0x1BD11BDAu;
  x0 += k0; x1 += k1;
  x0+=x1; x1=rotl32(x1,13); x1^=x0;  x0+=x1; x1=rotl32(x1,15); x1^=x0;
  x0+=x1; x1=rotl32(x1,26); x1^=x0;  x0+=x1; x1=rotl32(x1, 6); x1^=x0;
  x0+=k1; x1+=ks2+1u;
  x0+=x1; x1=rotl32(x1,17); x1^=x0;  x0+=x1; x1=rotl32(x1,29); x1^=x0;
  x0+=x1; x1=rotl32(x1,16); x1^=x0;  x0+=x1; x1=rotl32(x1,24); x1^=x0;
  x0+=ks2; x1+=k0+2u;
  x0+=x1; x1=rotl32(x1,13); x1^=x0;  x0+=x1; x1=rotl32(x1,15); x1^=x0;
  x0+=x1; x1=rotl32(x1,26); x1^=x0;  x0+=x1; x1=rotl32(x1, 6); x1^=x0;
  x0+=k0; x1+=k1+3u;
  x0+=x1; x1=rotl32(x1,17); x1^=x0;  x0+=x1; x1=rotl32(x1,29); x1^=x0;
  x0+=x1; x1=rotl32(x1,16); x1^=x0;  x0+=x1; x1=rotl32(x1,24); x1^=x0;
  x0+=k1; x1+=ks2+4u;
  x0+=x1; x1=rotl32(x1,13); x1^=x0;  x0+=x1; x1=rotl32(x1,15); x1^=x0;
  x0+=x1; x1=rotl32(x1,26); x1^=x0;  x0+=x1; x1=rotl32(x1, 6); x1^=x0;
  x0+=ks2; x1+=k0+5u;
  *o0 = x0; *o1 = x1;
}
__device__ __forceinline__ float part_unif(uint32_t ka, uint32_t kb, uint32_t idx){
  uint32_t o0,o1; tf2x32(ka,kb,0u,idx,&o0,&o1);
  uint32_t bits = o0 ^ o1;
  return __uint_as_float(0x3f800000u | (bits>>9)) - 1.0f;
}

// ---------------- helpers ----------------
__device__ __forceinline__ float bf2f(ushortT u){ return __uint_as_float(((uint32_t)u)<<16); }
__device__ __forceinline__ ushortT f2bf(float f){
  uint32_t x = __float_as_uint(f);
  return (ushortT)((x + 0x7fffu + ((x>>16)&1u)) >> 16);
}
__device__ __forceinline__ float sigm(float x){ return 1.0f/(1.0f+__expf(-x)); }
__device__ __forceinline__ f4v mfma16(s8v a, s8v b, f4v c){
  return __builtin_amdgcn_mfma_f32_16x16x32_bf16(a,b,c,0,0,0);
}
__device__ __forceinline__ s8v pack8(const float* p){
  s8v r;
  #pragma unroll
  for (int j=0;j<8;++j) r[j]=(short)f2bf(p[j]);
  return r;
}
// Coherent bypass loads (LLC coherence point) for cross-block mutable data.
__device__ __forceinline__ uint32_t ld32_sc1(const void* ptr){
  return __hip_atomic_load((uint32_t*)ptr, __ATOMIC_RELAXED, __HIP_MEMORY_SCOPE_AGENT);
}
__device__ __forceinline__ float ldf_sc1(const float* ptr){
  return __uint_as_float(ld32_sc1(ptr));
}
__device__ __forceinline__ s8v ld8_sc1(const ushortT* ptr){
  union { s8v v; unsigned long long q[2]; } u;
  u.q[0] = __hip_atomic_load((unsigned long long*)ptr,     __ATOMIC_RELAXED, __HIP_MEMORY_SCOPE_AGENT);
  u.q[1] = __hip_atomic_load((unsigned long long*)ptr + 1, __ATOMIC_RELAXED, __HIP_MEMORY_SCOPE_AGENT);
  return u.v;
}
// Write-through store to the LLC coherence point (no dirty L2 line anywhere).
__device__ __forceinline__ void st32_wt(void* ptr, uint32_t v){
  __hip_atomic_store((uint32_t*)ptr, v, __ATOMIC_RELAXED, __HIP_MEMORY_SCOPE_AGENT);
}
__device__ __forceinline__ void stf_wt(float* ptr, float v){
  st32_wt(ptr, __float_as_uint(v));
}

// ---------------- setup: bf16 copies + zero states + barrier reset ----------------
__global__ __launch_bounds__(256) void k_setup(
  const float* __restrict__ memory, const float* __restrict__ qw,
  const float* __restrict__ pjw,  const float* __restrict__ gw,
  ushortT* __restrict__ Mbf, ushortT* __restrict__ Wq, ushortT* __restrict__ Wpg,
  ushortT* __restrict__ AH0, ushortT* __restrict__ AH1,
  ushortT* __restrict__ DH0, ushortT* __restrict__ DH1,
  ushortT* __restrict__ CT0, ushortT* __restrict__ CT1,
  float* __restrict__ aw, float* __restrict__ awc,
  uint32_t* __restrict__ bars)
{
  int stride = gridDim.x*blockDim.x;
  int g0 = blockIdx.x*blockDim.x + threadIdx.x;
  for (int i=g0; i<32*400*512; i+=stride) Mbf[i]=f2bf(memory[i]);
  for (int i=g0; i<128*1024;  i+=stride) Wq[i]=f2bf(qw[i]);
  for (int i=g0; i<96*1536; i+=stride){
    int r=i/1536, k=i-r*1536;
    ushortT v=0;
    if (r<80) v=f2bf(pjw[r*1536+k]);
    else if (r==80) v=f2bf(gw[k]);
    Wpg[i]=v;
  }
  for (int i=g0; i<32*1024; i+=stride){ AH0[i]=0; AH1[i]=0; DH0[i]=0; DH1[i]=0; }
  for (int i=g0; i<32*512;  i+=stride){ CT0[i]=0; CT1[i]=0; }
  for (int i=g0; i<32*400;  i+=stride){ aw[i]=0.f; awc[i]=0.f; }
  if (g0 < 512) bars[g0]=0u;
}

// ---------------- fused prenet: two layers, 64 rows per block ----------------
__global__ __launch_bounds__(256) void k_prenet(
  const float* __restrict__ dec_inp, const float* __restrict__ w1, const float* __restrict__ w2,
  ushortT* __restrict__ preo,
  uint32_t k1a, uint32_t k1b, uint32_t k2a, uint32_t k2b)
{
  __shared__ ushortT Xs[64*96];
  __shared__ ushortT H1s[64*256];
  int tid=threadIdx.x, lane=tid&63, wv=tid>>6, quad=lane>>4, nl=lane&15;
  int r0 = blockIdx.x*64;
  for (int i=tid; i<64*96; i+=256){
    int rr=i/96, k=i-rr*96; int row=r0+rr; int s=row>>5, b=row&31;
    float v=0.f;
    if (k<80 && s>0) v = dec_inp[((size_t)b*80+k)*500 + (s-1)];
    Xs[i]=f2bf(v);
  }
  __syncthreads();
  f4v acc[4][4];
  #pragma unroll
  for (int mtl=0;mtl<4;++mtl)
    #pragma unroll
    for (int nt=0;nt<4;++nt) acc[mtl][nt]=(f4v){0,0,0,0};
  for (int kb=0;kb<3;++kb){
    int c0 = kb*32 + quad*8;
    s8v a[4];
    #pragma unroll
    for (int mtl=0;mtl<4;++mtl) a[mtl]=*(const s8v*)(Xs + (mtl*16+nl)*96 + c0);
    #pragma unroll
    for (int nt=0;nt<4;++nt){
      int rown = wv*64+nt*16+nl;
      s8v bb;
      if (c0 < 80) bb = pack8(w1 + (size_t)rown*80 + c0);
      else { s8v z={0,0,0,0,0,0,0,0}; bb=z; }
      #pragma unroll
      for (int mtl=0;mtl<4;++mtl) acc[mtl][nt]=mfma16(a[mtl],bb,acc[mtl][nt]);
    }
  }
  #pragma unroll
  for (int mtl=0;mtl<4;++mtl)
    #pragma unroll
    for (int nt=0;nt<4;++nt)
      #pragma unroll
      for (int r=0;r<4;++r){
        int mloc = mtl*16+quad*4+r;
        int col  = wv*64+nt*16+nl;
        float v = acc[mtl][nt][r]; v = v>0.f? v:0.f;
        uint32_t fidx = (uint32_t)(r0+mloc)*256u + (uint32_t)col;
        v = (part_unif(k1a,k1b,fidx) < 0.5f) ? v*2.0f : 0.0f;
        H1s[mloc*256+col]=f2bf(v);
      }
  __syncthreads();
  #pragma unroll
  for (int mtl=0;mtl<4;++mtl)
    #pragma unroll
    for (int nt=0;nt<4;++nt) acc[mtl][nt]=(f4v){0,0,0,0};
  for (int kb=0;kb<8;++kb){
    int c0 = kb*32 + quad*8;
    s8v a[4];
    #pragma unroll
    for (int mtl=0;mtl<4;++mtl) a[mtl]=*(const s8v*)(H1s + (mtl*16+nl)*256 + c0);
    #pragma unroll
    for (int nt=0;nt<4;++nt){
      int rown = wv*64+nt*16+nl;
      s8v bb = pack8(w2 + (size_t)rown*256 + c0);
      #pragma unroll
      for (int mtl=0;mtl<4;++mtl) acc[mtl][nt]=mfma16(a[mtl],bb,acc[mtl][nt]);
    }
  }
  #pragma unroll
  for (int mtl=0;mtl<4;++mtl)
    #pragma unroll
    for (int nt=0;nt<4;++nt)
      #pragma unroll
      for (int r=0;r<4;++r){
        int mloc = mtl*16+quad*4+r;
        int col  = wv*64+nt*16+nl;
        float v = acc[mtl][nt][r]; v = v>0.f? v:0.f;
        uint32_t fidx = (uint32_t)(r0+mloc)*256u + (uint32_t)col;
        v = (part_unif(k2a,k2b,fidx) < 0.5f) ? v*2.0f : 0.0f;
        preo[(size_t)(r0+mloc)*256+col]=f2bf(v);
      }
}

// ---------------- processed_memory: fp32 VALU GEMM (one-shot) ----------------
__global__ __launch_bounds__(256) void k_pm(
  const float* __restrict__ memory, const float* __restrict__ mw, float* __restrict__ pm)
{
  int row = blockIdx.x*2 + (threadIdx.x>>7);
  int col = threadIdx.x & 127;
  const float* mr = memory + (size_t)row*512;
  const float* wr = mw + (size_t)col*512;
  float acc=0.f;
  for (int k=0;k<512;k+=4){
    float4 a=*(const float4*)(mr+k), b=*(const float4*)(wr+k);
    acc += a.x*b.x + a.y*b.y + a.z*b.z + a.w*b.w;
  }
  pm[(size_t)row*128+col]=acc;
}

// ---------------- persistent cooperative decoder ----------------
struct PArgs {
  const float* awih; const float* awhh; const float* abih; const float* abhh;
  const float* dwih; const float* dwhh; const float* dbih; const float* dbhh;
  const float* lcw;  const float* llw;  const float* vw;
  const float* pjb;  const float* gb;
  const float* pm;   const int* mlen;
  const ushortT* preo; const ushortT* Wq; const ushortT* Wpg; const ushortT* Mbf;
  ushortT* AH0; ushortT* AH1; ushortT* DH0; ushortT* DH1; ushortT* CT0; ushortT* CT1;
  float* aw; float* awc; float* ebuf;
  float* out_mel; float* out_gate; float* out_align;
  uint32_t* bars;
  uint32_t katt_a, katt_b, kdec_a, kdec_b;
};

// Hierarchical grid barrier, fence-free: all cross-block mutable data is
// written with sc1 write-through stores, and __syncthreads() drains each
// wave's vmcnt (compiler emits s_waitcnt before s_barrier) -> stores are
// at the LLC before any wave arrives.  Readers use sc1 bypass loads.
__device__ __forceinline__ void gridbar(uint32_t* bars, uint32_t* myg){
  __syncthreads();
  if (threadIdx.x == 0){
    uint32_t g = *myg + 1u; *myg = g;
    uint32_t* gc  = bars + 32u*(blockIdx.x & 7u);
    uint32_t* mc  = bars + 256u;
    uint32_t* gen = bars + 288u;
    uint32_t prev = __hip_atomic_fetch_add(gc,1u,__ATOMIC_RELAXED,__HIP_MEMORY_SCOPE_AGENT);
    bool setter=false;
    if (prev == g*32u - 1u){
      uint32_t p2 = __hip_atomic_fetch_add(mc,1u,__ATOMIC_RELAXED,__HIP_MEMORY_SCOPE_AGENT);
      if (p2 == g*8u - 1u){
        __hip_atomic_store(gen, g, __ATOMIC_RELAXED, __HIP_MEMORY_SCOPE_AGENT);
        setter=true;
      }
    }
    if (!setter){
      while (__hip_atomic_load(gen, __ATOMIC_RELAXED, __HIP_MEMORY_SCOPE_AGENT) < g){
        __builtin_amdgcn_s_sleep(2);
      }
    }
  }
  __syncthreads();
}

__global__ __launch_bounds__(256,1) void k_persist(PArgs p){
  // LDS bytes: Wa 57600 + Wd 82176 + gbufA 4224 + gbufD 4224 + acst 512 + dcst 512
  //          + biasA 64 + biasD 64 + stg 256 + sc 12800 = 162,432  (<= 163,840)
  __shared__ ushortT Wa[16*1800];       // att rows: [preo 0..255 | ctx 256..767 | ah 768..1791]
  __shared__ ushortT Wd[16*2568];       // dec rows: [ah 0..1023 | ctx 1024..1535 | dh 1536..2559]
  __shared__ float gbufA[2][16][33];    // P1: att gate partials; P2: xA; P3: pv+red
  __shared__ float gbufD[2][16][33];    // P1: dec gate partials; P2: xD
  __shared__ float acst[4][32];
  __shared__ float dcst[4][32];
  __shared__ float biasA[16];
  __shared__ float biasD[16];
  __shared__ ushortT ahstg[4][32];      // P1 epilogue staging for packed write-through
  __shared__ ushortT dhstg[4][32];
  __shared__ float sc[3200];            // P2: locl[3200]; P2-proj: [0..1023]; P3: ctx partials[256]

  const int tid = threadIdx.x;
  const int bid = blockIdx.x;
  const int lane = tid & 63;
  const int wv = tid >> 6;
  const int quad = lane >> 4;
  const int nl = lane & 15;
  const int mt = wv & 1;       // batch half
  const int kh = wv >> 1;      // K half

  // ---- one-time init: weights fp32 -> bf16 LDS, states ----
  for (int rl=0; rl<16; ++rl){
    const int r = (rl>>2)*1024 + bid*4 + (rl&3);   // gate-major rows, 4 units/block
    for (int c=tid; c<1792; c+=256){
      float v = (c<768) ? p.awih[(size_t)r*768+c] : p.awhh[(size_t)r*1024+(c-768)];
      Wa[rl*1800+c] = f2bf(v);
    }
    for (int c=tid; c<2560; c+=256){
      float v = (c<1536) ? p.dwih[(size_t)r*1536+c] : p.dwhh[(size_t)r*1024+(c-1536)];
      Wd[rl*2568+c] = f2bf(v);
    }
  }
  if (tid < 16){
    int g=tid>>2, u=bid*4+(tid&3);
    biasA[tid]=p.abih[g*1024+u]+p.abhh[g*1024+u];
    biasD[tid]=p.dbih[g*1024+u]+p.dbhh[g*1024+u];
  }
  if (tid < 128){ acst[tid>>5][tid&31]=0.f; dcst[tid>>5][tid&31]=0.f; }
  __syncthreads();

  uint32_t myg = 0;

  for (int t=0; t<=TOUT; ++t){
    const ushortT* AHp = (t&1)? p.AH0 : p.AH1;   // AH(t-1)
    ushortT*       AHn = (t&1)? p.AH1 : p.AH0;   // AH(t)
    const ushortT* DHi = (t&1)? p.DH1 : p.DH0;   // DH(t-2)
    ushortT*       DHo = (t&1)? p.DH0 : p.DH1;   // DH(t-1)
    const ushortT* CTXp= (t&1)? p.CT1 : p.CT0;   // ctx(t-1)
    ushortT*       CTXn= (t&1)? p.CT0 : p.CT1;   // ctx(t)

    // ================= P1: att-LSTM(t) || dec-LSTM(t-1) =================
    const int arow = mt*16 + nl;   // batch row for A fragments
    if (t < TOUT){
      const ushortT* Xp = p.preo + ((size_t)t*32 + arow)*256 + quad*8;
      const ushortT* Xc = CTXp + arow*512 + quad*8;
      const ushortT* Xa = AHp + arow*1024 + quad*8;
      const ushortT* wr = Wa + nl*1800 + quad*8;
      f4v acc = {0.f,0.f,0.f,0.f};
      if (kh==0){
        #pragma unroll
        for (int kb=0;kb<8;++kb)  acc = mfma16(*(const s8v*)(Xp+kb*32), *(const s8v*)(wr+kb*32), acc);
        #pragma unroll
        for (int kb=0;kb<16;kb+=4){
          s8v x0=ld8_sc1(Xc+kb*32), x1=ld8_sc1(Xc+(kb+1)*32), x2=ld8_sc1(Xc+(kb+2)*32), x3=ld8_sc1(Xc+(kb+3)*32);
          acc = mfma16(x0, *(const s8v*)(wr+256+kb*32), acc);
          acc = mfma16(x1, *(const s8v*)(wr+256+(kb+1)*32), acc);
          acc = mfma16(x2, *(const s8v*)(wr+256+(kb+2)*32), acc);
          acc = mfma16(x3, *(const s8v*)(wr+256+(kb+3)*32), acc);
        }
        #pragma unroll
        for (int kb=0;kb<4;++kb)  acc = mfma16(ld8_sc1(Xa+kb*32), *(const s8v*)(wr+768+kb*32), acc);
      } else {
        #pragma unroll
        for (int kb=0;kb<28;kb+=4){
          s8v x0=ld8_sc1(Xa+128+kb*32), x1=ld8_sc1(Xa+128+(kb+1)*32), x2=ld8_sc1(Xa+128+(kb+2)*32), x3=ld8_sc1(Xa+128+(kb+3)*32);
          acc = mfma16(x0, *(const s8v*)(wr+896+kb*32), acc);
          acc = mfma16(x1, *(const s8v*)(wr+896+(kb+1)*32), acc);
          acc = mfma16(x2, *(const s8v*)(wr+896+(kb+2)*32), acc);
          acc = mfma16(x3, *(const s8v*)(wr+896+(kb+3)*32), acc);
        }
      }
      #pragma unroll
      for (int r4=0;r4<4;++r4) gbufA[kh][nl][mt*16+quad*4+r4]=acc[r4];
    }
    if (t >= 1){
      const ushortT* Xa = AHp + arow*1024 + quad*8;
      const ushortT* Xc = CTXp + arow*512 + quad*8;
      const ushortT* Xd = DHi + arow*1024 + quad*8;
      const ushortT* wr = Wd + nl*2568 + quad*8;
      f4v acc = {0.f,0.f,0.f,0.f};
      if (kh==0){
        #pragma unroll
        for (int kb=0;kb<32;kb+=4){
          s8v x0=ld8_sc1(Xa+kb*32), x1=ld8_sc1(Xa+(kb+1)*32), x2=ld8_sc1(Xa+(kb+2)*32), x3=ld8_sc1(Xa+(kb+3)*32);
          acc = mfma16(x0, *(const s8v*)(wr+kb*32), acc);
          acc = mfma16(x1, *(const s8v*)(wr+(kb+1)*32), acc);
          acc = mfma16(x2, *(const s8v*)(wr+(kb+2)*32), acc);
          acc = mfma16(x3, *(const s8v*)(wr+(kb+3)*32), acc);
        }
        #pragma unroll
        for (int kb=0;kb<8;kb+=4){
          s8v x0=ld8_sc1(Xc+kb*32), x1=ld8_sc1(Xc+(kb+1)*32), x2=ld8_sc1(Xc+(kb+2)*32), x3=ld8_sc1(Xc+(kb+3)*32);
          acc = mfma16(x0, *(const s8v*)(wr+1024+kb*32), acc);
          acc = mfma16(x1, *(const s8v*)(wr+1024+(kb+1)*32), acc);
          acc = mfma16(x2, *(const s8v*)(wr+1024+(kb+2)*32), acc);
          acc = mfma16(x3, *(const s8v*)(wr+1024+(kb+3)*32), acc);
        }
      } else {
        #pragma unroll
        for (int kb=0;kb<8;kb+=4){
          s8v x0=ld8_sc1(Xc+256+kb*32), x1=ld8_sc1(Xc+256+(kb+1)*32), x2=ld8_sc1(Xc+256+(kb+2)*32), x3=ld8_sc1(Xc+256+(kb+3)*32);
          acc = mfma16(x0, *(const s8v*)(wr+1280+kb*32), acc);
          acc = mfma16(x1, *(const s8v*)(wr+1280+(kb+1)*32), acc);
          acc = mfma16(x2, *(const s8v*)(wr+1280+(kb+2)*32), acc);
          acc = mfma16(x3, *(const s8v*)(wr+1280+(kb+3)*32), acc);
        }
        #pragma unroll
        for (int kb=0;kb<32;kb+=4){
          s8v x0=ld8_sc1(Xd+kb*32), x1=ld8_sc1(Xd+(kb+1)*32), x2=ld8_sc1(Xd+(kb+2)*32), x3=ld8_sc1(Xd+(kb+3)*32);
          acc = mfma16(x0, *(const s8v*)(wr+1536+kb*32), acc);
          acc = mfma16(x1, *(const s8v*)(wr+1536+(kb+1)*32), acc);
          acc = mfma16(x2, *(const s8v*)(wr+1536+(kb+2)*32), acc);
          acc = mfma16(x3, *(const s8v*)(wr+1536+(kb+3)*32), acc);
        }
      }
      #pragma unroll
      for (int r4=0;r4<4;++r4) gbufD[kh][nl][mt*16+quad*4+r4]=acc[r4];
    }
    __syncthreads();
    if (t < TOUT && tid < 128){
      const int uu=tid>>5, b=tid&31, u=bid*4+uu;
      float gi=gbufA[0][uu][b]   +gbufA[1][uu][b]   +biasA[uu];
      float gf=gbufA[0][4+uu][b] +gbufA[1][4+uu][b] +biasA[4+uu];
      float gg=gbufA[0][8+uu][b] +gbufA[1][8+uu][b] +biasA[8+uu];
      float go=gbufA[0][12+uu][b]+gbufA[1][12+uu][b]+biasA[12+uu];
      float cp=acst[uu][b];
      float c2=sigm(gf)*cp+sigm(gi)*tanhf(gg);
      float h =sigm(go)*tanhf(c2);
      uint32_t fidx=((uint32_t)(t*32+b))*1024u+(uint32_t)u;
      h=(part_unif(p.katt_a,p.katt_b,fidx)<0.9f)? h*(1.0f/0.9f):0.f;
      acst[uu][b]=c2;
      ahstg[uu][b]=f2bf(h);
    }
    if (t >= 1 && tid >= 128){
      const int uu=(tid>>5)&3, b=tid&31, u=bid*4+uu;
      float gi=gbufD[0][uu][b]   +gbufD[1][uu][b]   +biasD[uu];
      float gf=gbufD[0][4+uu][b] +gbufD[1][4+uu][b] +biasD[4+uu];
      float gg=gbufD[0][8+uu][b] +gbufD[1][8+uu][b] +biasD[8+uu];
      float go=gbufD[0][12+uu][b]+gbufD[1][12+uu][b]+biasD[12+uu];
      float cp=dcst[uu][b];
      float c2=sigm(gf)*cp+sigm(gi)*tanhf(gg);
      float h =sigm(go)*tanhf(c2);
      uint32_t fidx=((uint32_t)((t-1)*32+b))*1024u+(uint32_t)u;
      h=(part_unif(p.kdec_a,p.kdec_b,fidx)<0.9f)? h*(1.0f/0.9f):0.f;
      dcst[uu][b]=c2;
      dhstg[uu][b]=f2bf(h);
    }
    __syncthreads();
    // pack pairs and write-through to LLC (32-bit aligned stores)
    if (t < TOUT && tid < 64){
      const int b=tid>>1, pp=tid&1;
      uint32_t wd = (uint32_t)ahstg[2*pp][b] | ((uint32_t)ahstg[2*pp+1][b]<<16);
      st32_wt((uint32_t*)(AHn + b*1024 + bid*4) + pp, wd);
    }
    if (t >= 1 && tid >= 64 && tid < 128){
      const int j=tid-64, b=j>>1, pp=j&1;
      uint32_t wd = (uint32_t)dhstg[2*pp][b] | ((uint32_t)dhstg[2*pp+1][b]<<16);
      st32_wt((uint32_t*)(DHo + b*1024 + bid*4) + pp, wd);
    }
    gridbar(p.bars,&myg);

    // ================= P2: attention energies (blocks 0..127 = b x 100-pos chunk)
    //                      || projection(t-1) (blocks 128..133) =================
    if (bid < 128){
      if (t < TOUT){
        const int b = bid>>2, ch = bid&3, t0 = ch*100;
        float* xA = (float*)gbufA;          // [0..511] sAH(ushort x1024), [512..767] pq2, [768..895] pqs
        float* xD = (float*)gbufD;          // [0..129] awp, [130..259] awcp, [260..459] epart
        ushortT* sAH = (ushortT*)xA;
        // stage ah(t) via sc1 (mutable) + halo of aw/awc(t-1) via sc1
        {
          const uint32_t* ahsrc = (const uint32_t*)(AHn + b*1024);
          for (int i=tid;i<512;i+=256) ((uint32_t*)sAH)[i] = ld32_sc1(ahsrc + i);
        }
        for (int i=tid;i<130;i+=256){
          int tt=t0-15+i; float a_=0.f,c_=0.f;
          if (tt>=0 && tt<TIN){ a_=ldf_sc1(p.aw + b*TIN+tt); c_=ldf_sc1(p.awc + b*TIN+tt); }
          xD[i]=a_; xD[130+i]=c_;
        }
        __syncthreads();
        { // pq = query_w @ ah (bf16 x bf16, fp32 accum)  [r5-proven]
          const int a=tid&127, half=tid>>7;
          const ushortT* qr = p.Wq + a*1024 + half*512;
          const ushortT* hr = sAH + half*512;
          float acc=0.f;
          for (int k=0;k<512;k+=8){
            s8v q=*(const s8v*)(qr+k);
            s8v h=*(const s8v*)(hr+k);
            #pragma unroll
            for (int j=0;j<8;++j) acc += bf2f((ushortT)q[j])*bf2f((ushortT)h[j]);
          }
          xA[512+tid]=acc;
        }
        // conv -> locl[tl*32+f], tl in [0,100)  [r0-B1 geometry, direct-global lcw]
        for (int it=tid; it<3200; it+=256){
          const int tl=it>>5, f=it&31;
          const float* c0p=p.lcw + (f*2)*31;
          const float* c1p=c0p + 31;
          float s=0.f;
          #pragma unroll
          for (int j=0;j<31;++j) s += xD[tl+j]*c0p[j] + xD[130+tl+j]*c1p[j];
          sc[tl*32+f]=s;
        }
        __syncthreads();
        if (tid<128) xA[768+tid]=xA[512+tid]+xA[512+128+tid];
        __syncthreads();
        // energies [r0-B1 per-wave reduce], exp [r2/r5-proven no-max]
        {
          const int a_=tid&127, g=tid>>7, wid=tid>>6;
          float lw_r[32];
          #pragma unroll
          for (int j=0;j<32;++j) lw_r[j]=p.llw[a_*32+j];
          const float vr = p.vw[a_];
          const float pqa = xA[768+a_];
          for (int tl=g; tl<100; tl+=2){
            const float* lt = sc + tl*32;
            float l2=0.f;
            #pragma unroll
            for (int f=0;f<32;++f) l2 += lt[f]*lw_r[f];
            float x = pqa + l2 + p.pm[((size_t)b*TIN + (t0+tl))*128 + a_];
            x = fminf(fmaxf(x,-30.f),30.f);
            float ex = __expf(2.f*x);
            float cv = vr*((ex-1.f)*__builtin_amdgcn_rcpf(ex+1.f));
            #pragma unroll
            for (int o=32;o>0;o>>=1) cv += __shfl_xor(cv,o);
            if ((tid&63)==0) xD[260 + tl*2 + (wid&1)]=cv;
          }
        }
        __syncthreads();
        if (tid<100){
          const int tg=t0+tid;
          float e = xD[260+tid*2] + xD[260+tid*2+1];
          float pv = (tg < p.mlen[b]) ? __expf(e) : 0.f;
          stf_wt(p.ebuf + b*TIN + tg, pv);
        }
      }
    } else if (bid < 134){
      if (t >= 1){
        const int td=t-1, rb=(bid-128)*16;
        const int mrow = nl + mt*16;
        const ushortT* br  = p.Wpg + (size_t)(rb+nl)*1536 + quad*8;
        const ushortT* dhp = DHo + (size_t)mrow*1024 + quad*8;
        const ushortT* cxp = CTXp + (size_t)mrow*512 + quad*8;
        f4v acc={0.f,0.f,0.f,0.f};
        for (int kb=0;kb<24;++kb){
          const int kk=kh*768+kb*32;
          s8v aa = (kk<1024)? ld8_sc1(dhp+kk) : ld8_sc1(cxp+(kk-1024));
          acc = mfma16(aa, *(const s8v*)(br+kk), acc);
        }
        #pragma unroll
        for (int r4=0;r4<4;++r4) sc[kh*512 + (mt*16+quad*4+r4)*16 + nl]=acc[r4];
        __syncthreads();
        for (int idx=tid; idx<512; idx+=256){
          const int m=idx>>4, n=idx&15, r=rb+n;
          float v=sc[m*16+n]+sc[512+m*16+n];
          if (r<80) p.out_mel[(size_t)(m*80+r)*500+td]=v+p.pjb[r];
          else if (r==80) p.out_gate[(size_t)m*500+td]=v+p.gb[0];
        }
      }
    }
    gridbar(p.bars,&myg);

    // ================= P3: normalize + context, all 256 blocks (b=bid>>3, s=bid&7) =========
    if (t < TOUT){
      const int b = bid>>3, s = bid&7;
      float* pv  = (float*)gbufA;     // [0..399]
      float* red = pv + 408;          // [408..411]
      for (int i=tid;i<TIN;i+=256) pv[i]=ldf_sc1(p.ebuf + b*TIN + i);
      __syncthreads();
      float ls=0.f;
      for (int i=tid;i<TIN;i+=256) ls+=pv[i];
      #pragma unroll
      for (int o=32;o>0;o>>=1) ls+=__shfl_xor(ls,o);
      if ((tid&63)==0) red[tid>>6]=ls;
      __syncthreads();
      const float S=red[0]+red[1]+red[2]+red[3];
      const float rS=(S>0.f)?1.0f/S:0.f;
      // context slice: dims [s*64, s*64+64), quarters of positions
      const int dl = tid&63, q = tid>>6;
      const int d = s*64 + dl;
      const ushortT* mb = p.Mbf + ((size_t)b*TIN + q*100)*512 + d;
      const float* pq_ = pv + q*100;
      float cc=0.f;
      #pragma unroll 4
      for (int tt=0;tt<100;++tt) cc += pq_[tt]*bf2f(mb[(size_t)tt*512]);
      sc[q*64+dl]=cc;
      __syncthreads();
      if (tid < 32){
        const int dl0=tid*2, dl1=dl0+1;
        float v0 = (sc[dl0]+sc[64+dl0]+sc[128+dl0]+sc[192+dl0])*rS;
        float v1 = (sc[dl1]+sc[64+dl1]+sc[128+dl1]+sc[192+dl1])*rS;
        uint32_t wd = (uint32_t)f2bf(v0) | ((uint32_t)f2bf(v1)<<16);
        st32_wt((uint32_t*)(CTXn + b*512 + s*64) + tid, wd);
      }
      if (s==0){
        for (int i=tid;i<TIN;i+=256){
          float a2 = pv[i]*rS;
          stf_wt(p.aw + b*TIN + i, a2);
          float oldc = ldf_sc1(p.awc + b*TIN + i);
          stf_wt(p.awc + b*TIN + i, oldc + a2);
          p.out_align[((size_t)b*500+t)*400+i]=a2;
        }
      }
    }
    gridbar(p.bars,&myg);
  }
}

// ---------------- host ----------------
extern "C" void kernel_launch(void* const* d_in, const int* in_sizes, int n_in,
                              void* d_out, int out_size, void* d_ws, size_t ws_size,
                              hipStream_t stream) {
  (void)in_sizes; (void)n_in; (void)out_size; (void)ws_size;
  const float* memory  = (const float*)d_in[0];
  const float* dec_inp = (const float*)d_in[1];
  const int*   mlen    = (const int*)d_in[2];
  const float* pw1     = (const float*)d_in[3];
  const float* pw2     = (const float*)d_in[4];
  const float* awih    = (const float*)d_in[5];
  const float* awhh    = (const float*)d_in[6];
  const float* abih    = (const float*)d_in[7];
  const float* abhh    = (const float*)d_in[8];
  const float* qw      = (const float*)d_in[9];
  const float* mw      = (const float*)d_in[10];
  const float* vw      = (const float*)d_in[11];
  const float* lcw     = (const float*)d_in[12];
  const float* llw     = (const float*)d_in[13];
  const float* dwih    = (const float*)d_in[14];
  const float* dwhh    = (const float*)d_in[15];
  const float* dbih    = (const float*)d_in[16];
  const float* dbhh    = (const float*)d_in[17];
  const float* pjw     = (const float*)d_in[18];
  const float* pjb     = (const float*)d_in[19];
  const float* gw      = (const float*)d_in[20];
  const float* gb      = (const float*)d_in[21];

  char* w = (char*)d_ws;
  size_t off=0;
  auto alloc = [&](size_t n)->char*{ char* p=w+off; off=(off+n+255)&~(size_t)255; return p; };
  ushortT* Mbf = (ushortT*)alloc(32UL*400*512*2);
  ushortT* Wq  = (ushortT*)alloc(128UL*1024*2);
  ushortT* Wpg = (ushortT*)alloc(96UL*1536*2);
  ushortT* preo= (ushortT*)alloc(16000UL*256*2);
  float*   pm  = (float*)alloc(12800UL*128*4);
  ushortT* AH0 = (ushortT*)alloc(32UL*1024*2);
  ushortT* AH1 = (ushortT*)alloc(32UL*1024*2);
  ushortT* DH0 = (ushortT*)alloc(32UL*1024*2);
  ushortT* DH1 = (ushortT*)alloc(32UL*1024*2);
  ushortT* CT0 = (ushortT*)alloc(32UL*512*2);
  ushortT* CT1 = (ushortT*)alloc(32UL*512*2);
  float*   aw  = (float*)alloc(12800UL*4);
  float*   awc = (float*)alloc(12800UL*4);
  float*   ebuf= (float*)alloc(12800UL*4);
  uint32_t* bars=(uint32_t*)alloc(2048);

  // JAX partitionable split(key(42), 4)
  uint32_t K[4][2];
  for (uint32_t i=0;i<4;++i) tf2x32(0u,42u,0u,i,&K[i][0],&K[i][1]);

  float* out_mel   = (float*)d_out;
  float* out_gate  = out_mel + 1280000;
  float* out_align = out_mel + 1296000;

  k_setup<<<1024,256,0,stream>>>(memory,qw,pjw,gw,Mbf,Wq,Wpg,AH0,AH1,DH0,DH1,CT0,CT1,aw,awc,bars);
  k_prenet<<<250,256,0,stream>>>(dec_inp, pw1, pw2, preo, K[0][0],K[0][1], K[1][0],K[1][1]);
  k_pm<<<6400,256,0,stream>>>(memory, mw, pm);

  PArgs pa;
  pa.awih=awih; pa.awhh=awhh; pa.abih=abih; pa.abhh=abhh;
  pa.dwih=dwih; pa.dwhh=dwhh; pa.dbih=dbih; pa.dbhh=dbhh;
  pa.lcw=lcw; pa.llw=llw; pa.vw=vw; pa.pjb=pjb; pa.gb=gb;
  pa.pm=pm; pa.mlen=mlen;
  pa.preo=preo; pa.Wq=Wq; pa.Wpg=Wpg; pa.Mbf=Mbf;
  pa.AH0=AH0; pa.AH1=AH1; pa.DH0=DH0; pa.DH1=DH1; pa.CT0=CT0; pa.CT1=CT1;
  pa.aw=aw; pa.awc=awc; pa.ebuf=ebuf;
  pa.out_mel=out_mel; pa.out_gate=out_gate; pa.out_align=out_align;
  pa.bars=bars;
  pa.katt_a=K[2][0]; pa.katt_b=K[2][1]; pa.kdec_a=K[3][0]; pa.kdec_b=K[3][1];

  void* kargs[] = { &pa };
  (void)hipLaunchCooperativeKernel((const void*)k_persist, dim3(256), dim3(256), kargs, 0u, stream);
}

// Round 12
// 41317.703 us; speedup vs baseline: 1.2346x; 1.2346x over previous
//
#include <hip/hip_runtime.h>
#include <cstdint>

typedef unsigned short ushortT;
typedef __attribute__((ext_vector_type(8))) short s8v;   // 8 bf16 (4 VGPRs)
typedef __attribute__((ext_vector_type(4))) float f4v;   // MFMA acc

#define TIN 400
#define TOUT 500

// ---------------- threefry2x32 (JAX, 20 rounds) ----------------
__host__ __device__ __forceinline__ uint32_t rotl32(uint32_t v, int r){ return (v<<r)|(v>>(32-r)); }
__host__ __device__ inline void tf2x32(uint32_t k0, uint32_t k1, uint32_t x0, uint32_t x1,
                                       uint32_t* o0, uint32_t* o1){
  uint32_t ks2 = k0 ^ k1 ^ 0x1BD11BDAu;
  x0 += k0; x1 += k1;
  x0+=x1; x1=rotl32(x1,13); x1^=x0;  x0+=x1; x1=rotl32(x1,15); x1^=x0;
  x0+=x1; x1=rotl32(x1,26); x1^=x0;  x0+=x1; x1=rotl32(x1, 6); x1^=x0;
  x0+=k1; x1+=ks2+1u;
  x0+=x1; x1=rotl32(x1,17); x1^=x0;  x0+=x1; x1=rotl32(x1,29); x1^=x0;
  x0+=x1; x1=rotl32(x1,16); x1^=x0;  x0+=x1; x1=rotl32(x1,24); x1^=x0;
  x0+=ks2; x1+=k0+2u;
  x0+=x1; x1=rotl32(x1,13); x1^=x0;  x0+=x1; x1=rotl32(x1,15); x1^=x0;
  x0+=x1; x1=rotl32(x1,26); x1^=x0;  x0+=x1; x1=rotl32(x1, 6); x1^=x0;
  x0+=k0; x1+=k1+3u;
  x0+=x1; x1=rotl32(x1,17); x1^=x0;  x0+=x1; x1=rotl32(x1,29); x1^=x0;
  x0+=x1; x1=rotl32(x1,16); x1^=x0;  x0+=x1; x1=rotl32(x1,24); x1^=x0;
  x0+=k1; x1+=ks2+4u;
  x0+=x1; x1=rotl32(x1,13); x1^=x0;  x0+=x1; x1=rotl32(x1,15); x1^=x0;
  x0+=x1; x1=rotl32(x1,26); x1^=x0;  x0+=x1; x1=rotl32(x1, 6); x1^=x0;
  x0+=ks2; x1+=k0+5u;
  *o0 = x0; *o1 = x1;
}
__device__ __forceinline__ float part_unif(uint32_t ka, uint32_t kb, uint32_t idx){
  uint32_t o0,o1; tf2x32(ka,kb,0u,idx,&o0,&o1);
  uint32_t bits = o0 ^ o1;
  return __uint_as_float(0x3f800000u | (bits>>9)) - 1.0f;
}

// ---------------- helpers ----------------
__device__ __forceinline__ float bf2f(ushortT u){ return __uint_as_float(((uint32_t)u)<<16); }
__device__ __forceinline__ ushortT f2bf(float f){
  uint32_t x = __float_as_uint(f);
  return (ushortT)((x + 0x7fffu + ((x>>16)&1u)) >> 16);
}
__device__ __forceinline__ float sigm(float x){ return 1.0f/(1.0f+__expf(-x)); }
__device__ __forceinline__ f4v mfma16(s8v a, s8v b, f4v c){
  return __builtin_amdgcn_mfma_f32_16x16x32_bf16(a,b,c,0,0,0);
}
__device__ __forceinline__ s8v pack8(const float* p){
  s8v r;
  #pragma unroll
  for (int j=0;j<8;++j) r[j]=(short)f2bf(p[j]);
  return r;
}
// Coherent bypass loads (LLC coherence point) for cross-block mutable data.
// NOTE: keep these ADJACENT to their uses (inline or <=4-wide batches).
// Large preload clusters / re-grouping caused r10/r11 correctness failures.
__device__ __forceinline__ uint32_t ld32_sc1(const void* ptr){
  return __hip_atomic_load((uint32_t*)ptr, __ATOMIC_RELAXED, __HIP_MEMORY_SCOPE_AGENT);
}
__device__ __forceinline__ float ldf_sc1(const float* ptr){
  return __uint_as_float(ld32_sc1(ptr));
}
__device__ __forceinline__ s8v ld8_sc1(const ushortT* ptr){
  union { s8v v; unsigned long long q[2]; } u;
  u.q[0] = __hip_atomic_load((unsigned long long*)ptr,     __ATOMIC_RELAXED, __HIP_MEMORY_SCOPE_AGENT);
  u.q[1] = __hip_atomic_load((unsigned long long*)ptr + 1, __ATOMIC_RELAXED, __HIP_MEMORY_SCOPE_AGENT);
  return u.v;
}

// ---------------- setup: bf16 copies + zero states + barrier reset ----------------
__global__ __launch_bounds__(256) void k_setup(
  const float* __restrict__ memory, const float* __restrict__ qw,
  const float* __restrict__ pjw,  const float* __restrict__ gw,
  ushortT* __restrict__ Mbf, ushortT* __restrict__ Wq, ushortT* __restrict__ Wpg,
  ushortT* __restrict__ AH0, ushortT* __restrict__ AH1,
  ushortT* __restrict__ DH0, ushortT* __restrict__ DH1,
  ushortT* __restrict__ CT0, ushortT* __restrict__ CT1,
  float* __restrict__ aw, float* __restrict__ awc,
  uint32_t* __restrict__ bars)
{
  int stride = gridDim.x*blockDim.x;
  int g0 = blockIdx.x*blockDim.x + threadIdx.x;
  for (int i=g0; i<32*400*512; i+=stride) Mbf[i]=f2bf(memory[i]);
  for (int i=g0; i<128*1024;  i+=stride) Wq[i]=f2bf(qw[i]);
  for (int i=g0; i<96*1536; i+=stride){
    int r=i/1536, k=i-r*1536;
    ushortT v=0;
    if (r<80) v=f2bf(pjw[r*1536+k]);
    else if (r==80) v=f2bf(gw[k]);
    Wpg[i]=v;
  }
  for (int i=g0; i<32*1024; i+=stride){ AH0[i]=0; AH1[i]=0; DH0[i]=0; DH1[i]=0; }
  for (int i=g0; i<32*512;  i+=stride){ CT0[i]=0; CT1[i]=0; }
  for (int i=g0; i<32*400;  i+=stride){ aw[i]=0.f; awc[i]=0.f; }
  if (g0 < 512) bars[g0]=0u;
}

// ---------------- fused prenet: two layers, 64 rows per block ----------------
__global__ __launch_bounds__(256) void k_prenet(
  const float* __restrict__ dec_inp, const float* __restrict__ w1, const float* __restrict__ w2,
  ushortT* __restrict__ preo,
  uint32_t k1a, uint32_t k1b, uint32_t k2a, uint32_t k2b)
{
  __shared__ ushortT Xs[64*96];
  __shared__ ushortT H1s[64*256];
  int tid=threadIdx.x, lane=tid&63, wv=tid>>6, quad=lane>>4, nl=lane&15;
  int r0 = blockIdx.x*64;
  for (int i=tid; i<64*96; i+=256){
    int rr=i/96, k=i-rr*96; int row=r0+rr; int s=row>>5, b=row&31;
    float v=0.f;
    if (k<80 && s>0) v = dec_inp[((size_t)b*80+k)*500 + (s-1)];
    Xs[i]=f2bf(v);
  }
  __syncthreads();
  f4v acc[4][4];
  #pragma unroll
  for (int mtl=0;mtl<4;++mtl)
    #pragma unroll
    for (int nt=0;nt<4;++nt) acc[mtl][nt]=(f4v){0,0,0,0};
  for (int kb=0;kb<3;++kb){
    int c0 = kb*32 + quad*8;
    s8v a[4];
    #pragma unroll
    for (int mtl=0;mtl<4;++mtl) a[mtl]=*(const s8v*)(Xs + (mtl*16+nl)*96 + c0);
    #pragma unroll
    for (int nt=0;nt<4;++nt){
      int rown = wv*64+nt*16+nl;
      s8v bb;
      if (c0 < 80) bb = pack8(w1 + (size_t)rown*80 + c0);
      else { s8v z={0,0,0,0,0,0,0,0}; bb=z; }
      #pragma unroll
      for (int mtl=0;mtl<4;++mtl) acc[mtl][nt]=mfma16(a[mtl],bb,acc[mtl][nt]);
    }
  }
  #pragma unroll
  for (int mtl=0;mtl<4;++mtl)
    #pragma unroll
    for (int nt=0;nt<4;++nt)
      #pragma unroll
      for (int r=0;r<4;++r){
        int mloc = mtl*16+quad*4+r;
        int col  = wv*64+nt*16+nl;
        float v = acc[mtl][nt][r]; v = v>0.f? v:0.f;
        uint32_t fidx = (uint32_t)(r0+mloc)*256u + (uint32_t)col;
        v = (part_unif(k1a,k1b,fidx) < 0.5f) ? v*2.0f : 0.0f;
        H1s[mloc*256+col]=f2bf(v);
      }
  __syncthreads();
  #pragma unroll
  for (int mtl=0;mtl<4;++mtl)
    #pragma unroll
    for (int nt=0;nt<4;++nt) acc[mtl][nt]=(f4v){0,0,0,0};
  for (int kb=0;kb<8;++kb){
    int c0 = kb*32 + quad*8;
    s8v a[4];
    #pragma unroll
    for (int mtl=0;mtl<4;++mtl) a[mtl]=*(const s8v*)(H1s + (mtl*16+nl)*256 + c0);
    #pragma unroll
    for (int nt=0;nt<4;++nt){
      int rown = wv*64+nt*16+nl;
      s8v bb = pack8(w2 + (size_t)rown*256 + c0);
      #pragma unroll
      for (int mtl=0;mtl<4;++mtl) acc[mtl][nt]=mfma16(a[mtl],bb,acc[mtl][nt]);
    }
  }
  #pragma unroll
  for (int mtl=0;mtl<4;++mtl)
    #pragma unroll
    for (int nt=0;nt<4;++nt)
      #pragma unroll
      for (int r=0;r<4;++r){
        int mloc = mtl*16+quad*4+r;
        int col  = wv*64+nt*16+nl;
        float v = acc[mtl][nt][r]; v = v>0.f? v:0.f;
        uint32_t fidx = (uint32_t)(r0+mloc)*256u + (uint32_t)col;
        v = (part_unif(k2a,k2b,fidx) < 0.5f) ? v*2.0f : 0.0f;
        preo[(size_t)(r0+mloc)*256+col]=f2bf(v);
      }
}

// ---------------- processed_memory: fp32 VALU GEMM (one-shot) ----------------
__global__ __launch_bounds__(256) void k_pm(
  const float* __restrict__ memory, const float* __restrict__ mw, float* __restrict__ pm)
{
  int row = blockIdx.x*2 + (threadIdx.x>>7);
  int col = threadIdx.x & 127;
  const float* mr = memory + (size_t)row*512;
  const float* wr = mw + (size_t)col*512;
  float acc=0.f;
  for (int k=0;k<512;k+=4){
    float4 a=*(const float4*)(mr+k), b=*(const float4*)(wr+k);
    acc += a.x*b.x + a.y*b.y + a.z*b.z + a.w*b.w;
  }
  pm[(size_t)row*128+col]=acc;
}

// ---------------- persistent cooperative decoder ----------------
struct PArgs {
  const float* awih; const float* awhh; const float* abih; const float* abhh;
  const float* dwih; const float* dwhh; const float* dbih; const float* dbhh;
  const float* lcw;  const float* llw;  const float* vw;
  const float* pjb;  const float* gb;
  const float* pm;   const int* mlen;
  const ushortT* preo; const ushortT* Wq; const ushortT* Wpg; const ushortT* Mbf;
  ushortT* AH0; ushortT* AH1; ushortT* DH0; ushortT* DH1; ushortT* CT0; ushortT* CT1;
  float* aw; float* awc; float* ebuf;
  float* out_mel; float* out_gate; float* out_align;
  uint32_t* bars;
  uint32_t katt_a, katt_b, kdec_a, kdec_b;
};

// Hierarchical grid barrier (r8-proven): 8 group lines + master, monotonic.
// Release fence on arrival flushes plain stores to LLC; NO acquire fence —
// cross-block mutable data is read with sc1-bypass atomic loads.
__device__ __forceinline__ void gridbar(uint32_t* bars, uint32_t* myg){
  __syncthreads();
  if (threadIdx.x == 0){
    uint32_t g = *myg + 1u; *myg = g;
    __builtin_amdgcn_fence(__ATOMIC_RELEASE, "agent");
    uint32_t* gc  = bars + 32u*(blockIdx.x & 7u);
    uint32_t* mc  = bars + 256u;
    uint32_t* gen = bars + 288u;
    uint32_t prev = __hip_atomic_fetch_add(gc,1u,__ATOMIC_RELAXED,__HIP_MEMORY_SCOPE_AGENT);
    bool setter=false;
    if (prev == g*32u - 1u){
      uint32_t p2 = __hip_atomic_fetch_add(mc,1u,__ATOMIC_RELAXED,__HIP_MEMORY_SCOPE_AGENT);
      if (p2 == g*8u - 1u){
        __hip_atomic_store(gen, g, __ATOMIC_RELAXED, __HIP_MEMORY_SCOPE_AGENT);
        setter=true;
      }
    }
    if (!setter){
      while (__hip_atomic_load(gen, __ATOMIC_RELAXED, __HIP_MEMORY_SCOPE_AGENT) < g){
        __builtin_amdgcn_s_sleep(2);
      }
    }
  }
  __syncthreads();
}

__global__ __launch_bounds__(256,1) void k_persist(PArgs p){
  // LDS bytes: Wa 57600 + Wd 82176 + gbufA 4224 + gbufD 4224 + acst 512 + dcst 512
  //          + biasA 64 + biasD 64 + sc 13600  = 162,976  (<= 163,840)
  __shared__ ushortT Wa[16*1800];       // att rows: [preo 0..255 | ctx 256..767 | ah 768..1791]
  __shared__ ushortT Wd[16*2568];       // dec rows: [ah 0..1023 | ctx 1024..1535 | dh 1536..2559]
  __shared__ float gbufA[2][16][33];    // P1: att gate partials; P2: xA; P3: pv+red
  __shared__ float gbufD[2][16][33];    // P1: dec gate partials; P2: xD
  __shared__ float acst[4][32];
  __shared__ float dcst[4][32];
  __shared__ float biasA[16];
  __shared__ float biasD[16];
  __shared__ float sc[3400];            // P2: locl[3200]; P2-proj: [0..1023]; P3: ctx partials[256]

  const int tid = threadIdx.x;
  const int bid = blockIdx.x;
  const int lane = tid & 63;
  const int wv = tid >> 6;
  const int quad = lane >> 4;
  const int nl = lane & 15;
  const int mt = wv & 1;       // batch half
  const int kh = wv >> 1;      // K half

  // ---- one-time init: weights fp32 -> bf16 LDS, states ----
  for (int rl=0; rl<16; ++rl){
    const int r = (rl>>2)*1024 + bid*4 + (rl&3);   // gate-major rows, 4 units/block
    for (int c=tid; c<1792; c+=256){
      float v = (c<768) ? p.awih[(size_t)r*768+c] : p.awhh[(size_t)r*1024+(c-768)];
      Wa[rl*1800+c] = f2bf(v);
    }
    for (int c=tid; c<2560; c+=256){
      float v = (c<1536) ? p.dwih[(size_t)r*1536+c] : p.dwhh[(size_t)r*1024+(c-1536)];
      Wd[rl*2568+c] = f2bf(v);
    }
  }
  if (tid < 16){
    int g=tid>>2, u=bid*4+(tid&3);
    biasA[tid]=p.abih[g*1024+u]+p.abhh[g*1024+u];
    biasD[tid]=p.dbih[g*1024+u]+p.dbhh[g*1024+u];
  }
  if (tid < 128){ acst[tid>>5][tid&31]=0.f; dcst[tid>>5][tid&31]=0.f; }
  __syncthreads();

  uint32_t myg = 0;

  for (int t=0; t<=TOUT; ++t){
    const ushortT* AHp = (t&1)? p.AH0 : p.AH1;   // AH(t-1)
    ushortT*       AHn = (t&1)? p.AH1 : p.AH0;   // AH(t)
    const ushortT* DHi = (t&1)? p.DH1 : p.DH0;   // DH(t-2)
    ushortT*       DHo = (t&1)? p.DH0 : p.DH1;   // DH(t-1)
    const ushortT* CTXp= (t&1)? p.CT1 : p.CT0;   // ctx(t-1)
    ushortT*       CTXn= (t&1)? p.CT0 : p.CT1;   // ctx(t)

    // ================= P1: att-LSTM(t) || dec-LSTM(t-1) =================
    // sc1 loads 4-wide-batched, adjacent to uses (r8-proven pattern).
    const int arow = mt*16 + nl;   // batch row for A fragments
    if (t < TOUT){
      const ushortT* Xp = p.preo + ((size_t)t*32 + arow)*256 + quad*8;
      const ushortT* Xc = CTXp + arow*512 + quad*8;
      const ushortT* Xa = AHp + arow*1024 + quad*8;
      const ushortT* wr = Wa + nl*1800 + quad*8;
      f4v acc = {0.f,0.f,0.f,0.f};
      if (kh==0){
        #pragma unroll
        for (int kb=0;kb<8;++kb)  acc = mfma16(*(const s8v*)(Xp+kb*32), *(const s8v*)(wr+kb*32), acc);
        #pragma unroll
        for (int kb=0;kb<16;kb+=4){
          s8v x0=ld8_sc1(Xc+kb*32), x1=ld8_sc1(Xc+(kb+1)*32), x2=ld8_sc1(Xc+(kb+2)*32), x3=ld8_sc1(Xc+(kb+3)*32);
          acc = mfma16(x0, *(const s8v*)(wr+256+kb*32), acc);
          acc = mfma16(x1, *(const s8v*)(wr+256+(kb+1)*32), acc);
          acc = mfma16(x2, *(const s8v*)(wr+256+(kb+2)*32), acc);
          acc = mfma16(x3, *(const s8v*)(wr+256+(kb+3)*32), acc);
        }
        #pragma unroll
        for (int kb=0;kb<4;++kb)  acc = mfma16(ld8_sc1(Xa+kb*32), *(const s8v*)(wr+768+kb*32), acc);
      } else {
        #pragma unroll
        for (int kb=0;kb<28;kb+=4){
          s8v x0=ld8_sc1(Xa+128+kb*32), x1=ld8_sc1(Xa+128+(kb+1)*32), x2=ld8_sc1(Xa+128+(kb+2)*32), x3=ld8_sc1(Xa+128+(kb+3)*32);
          acc = mfma16(x0, *(const s8v*)(wr+896+kb*32), acc);
          acc = mfma16(x1, *(const s8v*)(wr+896+(kb+1)*32), acc);
          acc = mfma16(x2, *(const s8v*)(wr+896+(kb+2)*32), acc);
          acc = mfma16(x3, *(const s8v*)(wr+896+(kb+3)*32), acc);
        }
      }
      #pragma unroll
      for (int r4=0;r4<4;++r4) gbufA[kh][nl][mt*16+quad*4+r4]=acc[r4];
    }
    if (t >= 1){
      const ushortT* Xa = AHp + arow*1024 + quad*8;
      const ushortT* Xc = CTXp + arow*512 + quad*8;
      const ushortT* Xd = DHi + arow*1024 + quad*8;
      const ushortT* wr = Wd + nl*2568 + quad*8;
      f4v acc = {0.f,0.f,0.f,0.f};
      if (kh==0){
        #pragma unroll
        for (int kb=0;kb<32;kb+=4){
          s8v x0=ld8_sc1(Xa+kb*32), x1=ld8_sc1(Xa+(kb+1)*32), x2=ld8_sc1(Xa+(kb+2)*32), x3=ld8_sc1(Xa+(kb+3)*32);
          acc = mfma16(x0, *(const s8v*)(wr+kb*32), acc);
          acc = mfma16(x1, *(const s8v*)(wr+(kb+1)*32), acc);
          acc = mfma16(x2, *(const s8v*)(wr+(kb+2)*32), acc);
          acc = mfma16(x3, *(const s8v*)(wr+(kb+3)*32), acc);
        }
        #pragma unroll
        for (int kb=0;kb<8;kb+=4){
          s8v x0=ld8_sc1(Xc+kb*32), x1=ld8_sc1(Xc+(kb+1)*32), x2=ld8_sc1(Xc+(kb+2)*32), x3=ld8_sc1(Xc+(kb+3)*32);
          acc = mfma16(x0, *(const s8v*)(wr+1024+kb*32), acc);
          acc = mfma16(x1, *(const s8v*)(wr+1024+(kb+1)*32), acc);
          acc = mfma16(x2, *(const s8v*)(wr+1024+(kb+2)*32), acc);
          acc = mfma16(x3, *(const s8v*)(wr+1024+(kb+3)*32), acc);
        }
      } else {
        #pragma unroll
        for (int kb=0;kb<8;kb+=4){
          s8v x0=ld8_sc1(Xc+256+kb*32), x1=ld8_sc1(Xc+256+(kb+1)*32), x2=ld8_sc1(Xc+256+(kb+2)*32), x3=ld8_sc1(Xc+256+(kb+3)*32);
          acc = mfma16(x0, *(const s8v*)(wr+1280+kb*32), acc);
          acc = mfma16(x1, *(const s8v*)(wr+1280+(kb+1)*32), acc);
          acc = mfma16(x2, *(const s8v*)(wr+1280+(kb+2)*32), acc);
          acc = mfma16(x3, *(const s8v*)(wr+1280+(kb+3)*32), acc);
        }
        #pragma unroll
        for (int kb=0;kb<32;kb+=4){
          s8v x0=ld8_sc1(Xd+kb*32), x1=ld8_sc1(Xd+(kb+1)*32), x2=ld8_sc1(Xd+(kb+2)*32), x3=ld8_sc1(Xd+(kb+3)*32);
          acc = mfma16(x0, *(const s8v*)(wr+1536+kb*32), acc);
          acc = mfma16(x1, *(const s8v*)(wr+1536+(kb+1)*32), acc);
          acc = mfma16(x2, *(const s8v*)(wr+1536+(kb+2)*32), acc);
          acc = mfma16(x3, *(const s8v*)(wr+1536+(kb+3)*32), acc);
        }
      }
      #pragma unroll
      for (int r4=0;r4<4;++r4) gbufD[kh][nl][mt*16+quad*4+r4]=acc[r4];
    }
    __syncthreads();
    if (t < TOUT && tid < 128){
      const int uu=tid>>5, b=tid&31, u=bid*4+uu;
      float gi=gbufA[0][uu][b]   +gbufA[1][uu][b]   +biasA[uu];
      float gf=gbufA[0][4+uu][b] +gbufA[1][4+uu][b] +biasA[4+uu];
      float gg=gbufA[0][8+uu][b] +gbufA[1][8+uu][b] +biasA[8+uu];
      float go=gbufA[0][12+uu][b]+gbufA[1][12+uu][b]+biasA[12+uu];
      float cp=acst[uu][b];
      float c2=sigm(gf)*cp+sigm(gi)*tanhf(gg);
      float h =sigm(go)*tanhf(c2);
      uint32_t fidx=((uint32_t)(t*32+b))*1024u+(uint32_t)u;
      h=(part_unif(p.katt_a,p.katt_b,fidx)<0.9f)? h*(1.0f/0.9f):0.f;
      acst[uu][b]=c2;
      AHn[b*1024+u]=f2bf(h);
    }
    if (t >= 1 && tid >= 128){
      const int uu=(tid>>5)&3, b=tid&31, u=bid*4+uu;
      float gi=gbufD[0][uu][b]   +gbufD[1][uu][b]   +biasD[uu];
      float gf=gbufD[0][4+uu][b] +gbufD[1][4+uu][b] +biasD[4+uu];
      float gg=gbufD[0][8+uu][b] +gbufD[1][8+uu][b] +biasD[8+uu];
      float go=gbufD[0][12+uu][b]+gbufD[1][12+uu][b]+biasD[12+uu];
      float cp=dcst[uu][b];
      float c2=sigm(gf)*cp+sigm(gi)*tanhf(gg);
      float h =sigm(go)*tanhf(c2);
      uint32_t fidx=((uint32_t)((t-1)*32+b))*1024u+(uint32_t)u;
      h=(part_unif(p.kdec_a,p.kdec_b,fidx)<0.9f)? h*(1.0f/0.9f):0.f;
      dcst[uu][b]=c2;
      DHo[b*1024+u]=f2bf(h);
    }
    gridbar(p.bars,&myg);

    // ================= P2: attention energies (blocks 0..127 = b x 100-pos chunk)
    //                      || projection(t-1) (blocks 128..133) =================
    if (bid < 128){
      if (t < TOUT){
        const int b = bid>>2, ch = bid&3, t0 = ch*100;
        float* xA = (float*)gbufA;          // [0..511] sAH(ushort x1024), [512..767] pq2, [768..895] pqs
        float* xD = (float*)gbufD;          // [0..129] awp, [130..259] awcp, [260..459] epart
        ushortT* sAH = (ushortT*)xA;
        // stage ah(t) via sc1 (mutable) + halo of aw/awc(t-1) via sc1
        {
          const uint32_t* ahsrc = (const uint32_t*)(AHn + b*1024);
          for (int i=tid;i<512;i+=256) ((uint32_t*)sAH)[i] = ld32_sc1(ahsrc + i);
        }
        for (int i=tid;i<130;i+=256){
          int tt=t0-15+i; float a_=0.f,c_=0.f;
          if (tt>=0 && tt<TIN){ a_=ldf_sc1(p.aw + b*TIN+tt); c_=ldf_sc1(p.awc + b*TIN+tt); }
          xD[i]=a_; xD[130+i]=c_;
        }
        __syncthreads();
        { // pq = query_w @ ah (bf16 x bf16, fp32 accum)  [r5-proven]
          const int a=tid&127, half=tid>>7;
          const ushortT* qr = p.Wq + a*1024 + half*512;
          const ushortT* hr = sAH + half*512;
          float acc=0.f;
          for (int k=0;k<512;k+=8){
            s8v q=*(const s8v*)(qr+k);
            s8v h=*(const s8v*)(hr+k);
            #pragma unroll
            for (int j=0;j<8;++j) acc += bf2f((ushortT)q[j])*bf2f((ushortT)h[j]);
          }
          xA[512+tid]=acc;
        }
        // conv -> locl[tl*32+f], tl in [0,100)  [r0-B1 geometry, direct-global lcw]
        for (int it=tid; it<3200; it+=256){
          const int tl=it>>5, f=it&31;
          const float* c0p=p.lcw + (f*2)*31;
          const float* c1p=c0p + 31;
          float s=0.f;
          #pragma unroll
          for (int j=0;j<31;++j) s += xD[tl+j]*c0p[j] + xD[130+tl+j]*c1p[j];
          sc[tl*32+f]=s;
        }
        __syncthreads();
        if (tid<128) xA[768+tid]=xA[512+tid]+xA[512+128+tid];
        __syncthreads();
        // energies [r0-B1 per-wave reduce], exp [r2/r5-proven no-max]
        {
          const int a_=tid&127, g=tid>>7, wid=tid>>6;
          float lw_r[32];
          #pragma unroll
          for (int j=0;j<32;++j) lw_r[j]=p.llw[a_*32+j];
          const float vr = p.vw[a_];
          const float pqa = xA[768+a_];
          for (int tl=g; tl<100; tl+=2){
            const float* lt = sc + tl*32;
            float l2=0.f;
            #pragma unroll
            for (int f=0;f<32;++f) l2 += lt[f]*lw_r[f];
            float x = pqa + l2 + p.pm[((size_t)b*TIN + (t0+tl))*128 + a_];
            x = fminf(fmaxf(x,-30.f),30.f);
            float ex = __expf(2.f*x);
            float cv = vr*((ex-1.f)*__builtin_amdgcn_rcpf(ex+1.f));
            #pragma unroll
            for (int o=32;o>0;o>>=1) cv += __shfl_xor(cv,o);
            if ((tid&63)==0) xD[260 + tl*2 + (wid&1)]=cv;
          }
        }
        __syncthreads();
        if (tid<100){
          const int tg=t0+tid;
          float e = xD[260+tid*2] + xD[260+tid*2+1];
          float pv = (tg < p.mlen[b]) ? __expf(e) : 0.f;
          p.ebuf[b*TIN+tg]=pv;
        }
      }
    } else if (bid < 134){
      if (t >= 1){
        const int td=t-1, rb=(bid-128)*16;
        const int mrow = nl + mt*16;
        const ushortT* br  = p.Wpg + (size_t)(rb+nl)*1536 + quad*8;
        const ushortT* dhp = DHo + (size_t)mrow*1024 + quad*8;
        const ushortT* cxp = CTXp + (size_t)mrow*512 + quad*8;
        f4v acc={0.f,0.f,0.f,0.f};
        for (int kb=0;kb<24;++kb){
          const int kk=kh*768+kb*32;
          s8v aa = (kk<1024)? ld8_sc1(dhp+kk) : ld8_sc1(cxp+(kk-1024));
          acc = mfma16(aa, *(const s8v*)(br+kk), acc);
        }
        #pragma unroll
        for (int r4=0;r4<4;++r4) sc[kh*512 + (mt*16+quad*4+r4)*16 + nl]=acc[r4];
        __syncthreads();
        for (int idx=tid; idx<512; idx+=256){
          const int m=idx>>4, n=idx&15, r=rb+n;
          float v=sc[m*16+n]+sc[512+m*16+n];
          if (r<80) p.out_mel[(size_t)(m*80+r)*500+td]=v+p.pjb[r];
          else if (r==80) p.out_gate[(size_t)m*500+td]=v+p.gb[0];
        }
      }
    }
    gridbar(p.bars,&myg);

    // ================= P3: normalize + context, all 256 blocks (b=bid>>3, s=bid&7) =========
    if (t < TOUT){
      const int b = bid>>3, s = bid&7;
      float* pv  = (float*)gbufA;     // [0..399]
      float* red = pv + 408;          // [408..411]
      for (int i=tid;i<TIN;i+=256) pv[i]=ldf_sc1(p.ebuf + b*TIN + i);
      __syncthreads();
      float ls=0.f;
      for (int i=tid;i<TIN;i+=256) ls+=pv[i];
      #pragma unroll
      for (int o=32;o>0;o>>=1) ls+=__shfl_xor(ls,o);
      if ((tid&63)==0) red[tid>>6]=ls;
      __syncthreads();
      const float S=red[0]+red[1]+red[2]+red[3];
      const float rS=(S>0.f)?1.0f/S:0.f;
      // context slice: dims [s*64, s*64+64), quarters of positions
      const int dl = tid&63, q = tid>>6;
      const int d = s*64 + dl;
      const ushortT* mb = p.Mbf + ((size_t)b*TIN + q*100)*512 + d;
      const float* pq_ = pv + q*100;
      float cc=0.f;
      #pragma unroll 4
      for (int tt=0;tt<100;++tt) cc += pq_[tt]*bf2f(mb[(size_t)tt*512]);
      sc[q*64+dl]=cc;
      __syncthreads();
      if (q==0){
        float v = sc[dl]+sc[64+dl]+sc[128+dl]+sc[192+dl];
        CTXn[b*512+d]=f2bf(v*rS);
      }
      if (s==0){
        for (int i=tid;i<TIN;i+=256){
          float a2 = pv[i]*rS;
          p.aw[b*TIN+i]=a2;
          p.awc[b*TIN+i]+=a2;
          p.out_align[((size_t)b*500+t)*400+i]=a2;
        }
      }
    }
    gridbar(p.bars,&myg);
  }
}

// ---------------- host ----------------
extern "C" void kernel_launch(void* const* d_in, const int* in_sizes, int n_in,
                              void* d_out, int out_size, void* d_ws, size_t ws_size,
                              hipStream_t stream) {
  (void)in_sizes; (void)n_in; (void)out_size; (void)ws_size;
  const float* memory  = (const float*)d_in[0];
  const float* dec_inp = (const float*)d_in[1];
  const int*   mlen    = (const int*)d_in[2];
  const float* pw1     = (const float*)d_in[3];
  const float* pw2     = (const float*)d_in[4];
  const float* awih    = (const float*)d_in[5];
  const float* awhh    = (const float*)d_in[6];
  const float* abih    = (const float*)d_in[7];
  const float* abhh    = (const float*)d_in[8];
  const float* qw      = (const float*)d_in[9];
  const float* mw      = (const float*)d_in[10];
  const float* vw      = (const float*)d_in[11];
  const float* lcw     = (const float*)d_in[12];
  const float* llw     = (const float*)d_in[13];
  const float* dwih    = (const float*)d_in[14];
  const float* dwhh    = (const float*)d_in[15];
  const float* dbih    = (const float*)d_in[16];
  const float* dbhh    = (const float*)d_in[17];
  const float* pjw     = (const float*)d_in[18];
  const float* pjb     = (const float*)d_in[19];
  const float* gw      = (const float*)d_in[20];
  const float* gb      = (const float*)d_in[21];

  char* w = (char*)d_ws;
  size_t off=0;
  auto alloc = [&](size_t n)->char*{ char* p=w+off; off=(off+n+255)&~(size_t)255; return p; };
  ushortT* Mbf = (ushortT*)alloc(32UL*400*512*2);
  ushortT* Wq  = (ushortT*)alloc(128UL*1024*2);
  ushortT* Wpg = (ushortT*)alloc(96UL*1536*2);
  ushortT* preo= (ushortT*)alloc(16000UL*256*2);
  float*   pm  = (float*)alloc(12800UL*128*4);
  ushortT* AH0 = (ushortT*)alloc(32UL*1024*2);
  ushortT* AH1 = (ushortT*)alloc(32UL*1024*2);
  ushortT* DH0 = (ushortT*)alloc(32UL*1024*2);
  ushortT* DH1 = (ushortT*)alloc(32UL*1024*2);
  ushortT* CT0 = (ushortT*)alloc(32UL*512*2);
  ushortT* CT1 = (ushortT*)alloc(32UL*512*2);
  float*   aw  = (float*)alloc(12800UL*4);
  float*   awc = (float*)alloc(12800UL*4);
  float*   ebuf= (float*)alloc(12800UL*4);
  uint32_t* bars=(uint32_t*)alloc(2048);

  // JAX partitionable split(key(42), 4)
  uint32_t K[4][2];
  for (uint32_t i=0;i<4;++i) tf2x32(0u,42u,0u,i,&K[i][0],&K[i][1]);

  float* out_mel   = (float*)d_out;
  float* out_gate  = out_mel + 1280000;
  float* out_align = out_mel + 1296000;

  k_setup<<<1024,256,0,stream>>>(memory,qw,pjw,gw,Mbf,Wq,Wpg,AH0,AH1,DH0,DH1,CT0,CT1,aw,awc,bars);
  k_prenet<<<250,256,0,stream>>>(dec_inp, pw1, pw2, preo, K[0][0],K[0][1], K[1][0],K[1][1]);
  k_pm<<<6400,256,0,stream>>>(memory, mw, pm);

  PArgs pa;
  pa.awih=awih; pa.awhh=awhh; pa.abih=abih; pa.abhh=abhh;
  pa.dwih=dwih; pa.dwhh=dwhh; pa.dbih=dbih; pa.dbhh=dbhh;
  pa.lcw=lcw; pa.llw=llw; pa.vw=vw; pa.pjb=pjb; pa.gb=gb;
  pa.pm=pm; pa.mlen=mlen;
  pa.preo=preo; pa.Wq=Wq; pa.Wpg=Wpg; pa.Mbf=Mbf;
  pa.AH0=AH0; pa.AH1=AH1; pa.DH0=DH0; pa.DH1=DH1; pa.CT0=CT0; pa.CT1=CT1;
  pa.aw=aw; pa.awc=awc; pa.ebuf=ebuf;
  pa.out_mel=out_mel; pa.out_gate=out_gate; pa.out_align=out_align;
  pa.bars=bars;
  pa.katt_a=K[2][0]; pa.katt_b=K[2][1]; pa.kdec_a=K[3][0]; pa.kdec_b=K[3][1];

  void* kargs[] = { &pa };
  (void)hipLaunchCooperativeKernel((const void*)k_persist, dim3(256), dim3(256), kargs, 0u, stream);
}

// Round 13
// 40670.721 us; speedup vs baseline: 1.2542x; 1.0159x over previous
//
#include <hip/hip_runtime.h>
#include <cstdint>

typedef unsigned short ushortT;
typedef __attribute__((ext_vector_type(8))) short s8v;   // 8 bf16 (4 VGPRs)
typedef __attribute__((ext_vector_type(4))) float f4v;   // MFMA acc

#define TIN 400
#define TOUT 500

// ---------------- threefry2x32 (JAX, 20 rounds) ----------------
__host__ __device__ __forceinline__ uint32_t rotl32(uint32_t v, int r){ return (v<<r)|(v>>(32-r)); }
__host__ __device__ inline void tf2x32(uint32_t k0, uint32_t k1, uint32_t x0, uint32_t x1,
                                       uint32_t* o0, uint32_t* o1){
  uint32_t ks2 = k0 ^ k1 ^ 0x1BD11BDAu;
  x0 += k0; x1 += k1;
  x0+=x1; x1=rotl32(x1,13); x1^=x0;  x0+=x1; x1=rotl32(x1,15); x1^=x0;
  x0+=x1; x1=rotl32(x1,26); x1^=x0;  x0+=x1; x1=rotl32(x1, 6); x1^=x0;
  x0+=k1; x1+=ks2+1u;
  x0+=x1; x1=rotl32(x1,17); x1^=x0;  x0+=x1; x1=rotl32(x1,29); x1^=x0;
  x0+=x1; x1=rotl32(x1,16); x1^=x0;  x0+=x1; x1=rotl32(x1,24); x1^=x0;
  x0+=ks2; x1+=k0+2u;
  x0+=x1; x1=rotl32(x1,13); x1^=x0;  x0+=x1; x1=rotl32(x1,15); x1^=x0;
  x0+=x1; x1=rotl32(x1,26); x1^=x0;  x0+=x1; x1=rotl32(x1, 6); x1^=x0;
  x0+=k0; x1+=k1+3u;
  x0+=x1; x1=rotl32(x1,17); x1^=x0;  x0+=x1; x1=rotl32(x1,29); x1^=x0;
  x0+=x1; x1=rotl32(x1,16); x1^=x0;  x0+=x1; x1=rotl32(x1,24); x1^=x0;
  x0+=k1; x1+=ks2+4u;
  x0+=x1; x1=rotl32(x1,13); x1^=x0;  x0+=x1; x1=rotl32(x1,15); x1^=x0;
  x0+=x1; x1=rotl32(x1,26); x1^=x0;  x0+=x1; x1=rotl32(x1, 6); x1^=x0;
  x0+=ks2; x1+=k0+5u;
  *o0 = x0; *o1 = x1;
}
__device__ __forceinline__ float part_unif(uint32_t ka, uint32_t kb, uint32_t idx){
  uint32_t o0,o1; tf2x32(ka,kb,0u,idx,&o0,&o1);
  uint32_t bits = o0 ^ o1;
  return __uint_as_float(0x3f800000u | (bits>>9)) - 1.0f;
}

// ---------------- helpers ----------------
__device__ __forceinline__ float bf2f(ushortT u){ return __uint_as_float(((uint32_t)u)<<16); }
__device__ __forceinline__ ushortT f2bf(float f){
  uint32_t x = __float_as_uint(f);
  return (ushortT)((x + 0x7fffu + ((x>>16)&1u)) >> 16);
}
__device__ __forceinline__ float sigm(float x){ return 1.0f/(1.0f+__expf(-x)); }
__device__ __forceinline__ f4v mfma16(s8v a, s8v b, f4v c){
  return __builtin_amdgcn_mfma_f32_16x16x32_bf16(a,b,c,0,0,0);
}
__device__ __forceinline__ s8v pack8(const float* p){
  s8v r;
  #pragma unroll
  for (int j=0;j<8;++j) r[j]=(short)f2bf(p[j]);
  return r;
}
// Coherent bypass loads (LLC coherence point) for cross-block mutable data.
// NOTE: keep these ADJACENT to their uses (inline or <=4-wide batches).
// Large preload clusters / re-grouping caused r10/r11 correctness failures.
__device__ __forceinline__ uint32_t ld32_sc1(const void* ptr){
  return __hip_atomic_load((uint32_t*)ptr, __ATOMIC_RELAXED, __HIP_MEMORY_SCOPE_AGENT);
}
__device__ __forceinline__ float ldf_sc1(const float* ptr){
  return __uint_as_float(ld32_sc1(ptr));
}
__device__ __forceinline__ s8v ld8_sc1(const ushortT* ptr){
  union { s8v v; unsigned long long q[2]; } u;
  u.q[0] = __hip_atomic_load((unsigned long long*)ptr,     __ATOMIC_RELAXED, __HIP_MEMORY_SCOPE_AGENT);
  u.q[1] = __hip_atomic_load((unsigned long long*)ptr + 1, __ATOMIC_RELAXED, __HIP_MEMORY_SCOPE_AGENT);
  return u.v;
}

// ---------------- setup: bf16 copies + zero states + barrier reset ----------------
__global__ __launch_bounds__(256) void k_setup(
  const float* __restrict__ memory, const float* __restrict__ qw,
  const float* __restrict__ pjw,  const float* __restrict__ gw,
  ushortT* __restrict__ Mbf, ushortT* __restrict__ Wq, ushortT* __restrict__ Wpg,
  ushortT* __restrict__ AH0, ushortT* __restrict__ AH1,
  ushortT* __restrict__ DH0, ushortT* __restrict__ DH1,
  ushortT* __restrict__ CT0, ushortT* __restrict__ CT1,
  float* __restrict__ aw, float* __restrict__ awc,
  uint32_t* __restrict__ bars)
{
  int stride = gridDim.x*blockDim.x;
  int g0 = blockIdx.x*blockDim.x + threadIdx.x;
  for (int i=g0; i<32*400*512; i+=stride) Mbf[i]=f2bf(memory[i]);
  for (int i=g0; i<128*1024;  i+=stride) Wq[i]=f2bf(qw[i]);
  for (int i=g0; i<96*1536; i+=stride){
    int r=i/1536, k=i-r*1536;
    ushortT v=0;
    if (r<80) v=f2bf(pjw[r*1536+k]);
    else if (r==80) v=f2bf(gw[k]);
    Wpg[i]=v;
  }
  for (int i=g0; i<32*1024; i+=stride){ AH0[i]=0; AH1[i]=0; DH0[i]=0; DH1[i]=0; }
  for (int i=g0; i<32*512;  i+=stride){ CT0[i]=0; CT1[i]=0; }
  for (int i=g0; i<32*400;  i+=stride){ aw[i]=0.f; awc[i]=0.f; }
  if (g0 < 512) bars[g0]=0u;
}

// ---------------- fused prenet: two layers, 64 rows per block ----------------
__global__ __launch_bounds__(256) void k_prenet(
  const float* __restrict__ dec_inp, const float* __restrict__ w1, const float* __restrict__ w2,
  ushortT* __restrict__ preo,
  uint32_t k1a, uint32_t k1b, uint32_t k2a, uint32_t k2b)
{
  __shared__ ushortT Xs[64*96];
  __shared__ ushortT H1s[64*256];
  int tid=threadIdx.x, lane=tid&63, wv=tid>>6, quad=lane>>4, nl=lane&15;
  int r0 = blockIdx.x*64;
  for (int i=tid; i<64*96; i+=256){
    int rr=i/96, k=i-rr*96; int row=r0+rr; int s=row>>5, b=row&31;
    float v=0.f;
    if (k<80 && s>0) v = dec_inp[((size_t)b*80+k)*500 + (s-1)];
    Xs[i]=f2bf(v);
  }
  __syncthreads();
  f4v acc[4][4];
  #pragma unroll
  for (int mtl=0;mtl<4;++mtl)
    #pragma unroll
    for (int nt=0;nt<4;++nt) acc[mtl][nt]=(f4v){0,0,0,0};
  for (int kb=0;kb<3;++kb){
    int c0 = kb*32 + quad*8;
    s8v a[4];
    #pragma unroll
    for (int mtl=0;mtl<4;++mtl) a[mtl]=*(const s8v*)(Xs + (mtl*16+nl)*96 + c0);
    #pragma unroll
    for (int nt=0;nt<4;++nt){
      int rown = wv*64+nt*16+nl;
      s8v bb;
      if (c0 < 80) bb = pack8(w1 + (size_t)rown*80 + c0);
      else { s8v z={0,0,0,0,0,0,0,0}; bb=z; }
      #pragma unroll
      for (int mtl=0;mtl<4;++mtl) acc[mtl][nt]=mfma16(a[mtl],bb,acc[mtl][nt]);
    }
  }
  #pragma unroll
  for (int mtl=0;mtl<4;++mtl)
    #pragma unroll
    for (int nt=0;nt<4;++nt)
      #pragma unroll
      for (int r=0;r<4;++r){
        int mloc = mtl*16+quad*4+r;
        int col  = wv*64+nt*16+nl;
        float v = acc[mtl][nt][r]; v = v>0.f? v:0.f;
        uint32_t fidx = (uint32_t)(r0+mloc)*256u + (uint32_t)col;
        v = (part_unif(k1a,k1b,fidx) < 0.5f) ? v*2.0f : 0.0f;
        H1s[mloc*256+col]=f2bf(v);
      }
  __syncthreads();
  #pragma unroll
  for (int mtl=0;mtl<4;++mtl)
    #pragma unroll
    for (int nt=0;nt<4;++nt) acc[mtl][nt]=(f4v){0,0,0,0};
  for (int kb=0;kb<8;++kb){
    int c0 = kb*32 + quad*8;
    s8v a[4];
    #pragma unroll
    for (int mtl=0;mtl<4;++mtl) a[mtl]=*(const s8v*)(H1s + (mtl*16+nl)*256 + c0);
    #pragma unroll
    for (int nt=0;nt<4;++nt){
      int rown = wv*64+nt*16+nl;
      s8v bb = pack8(w2 + (size_t)rown*256 + c0);
      #pragma unroll
      for (int mtl=0;mtl<4;++mtl) acc[mtl][nt]=mfma16(a[mtl],bb,acc[mtl][nt]);
    }
  }
  #pragma unroll
  for (int mtl=0;mtl<4;++mtl)
    #pragma unroll
    for (int nt=0;nt<4;++nt)
      #pragma unroll
      for (int r=0;r<4;++r){
        int mloc = mtl*16+quad*4+r;
        int col  = wv*64+nt*16+nl;
        float v = acc[mtl][nt][r]; v = v>0.f? v:0.f;
        uint32_t fidx = (uint32_t)(r0+mloc)*256u + (uint32_t)col;
        v = (part_unif(k2a,k2b,fidx) < 0.5f) ? v*2.0f : 0.0f;
        preo[(size_t)(r0+mloc)*256+col]=f2bf(v);
      }
}

// ---------------- processed_memory: fp32 VALU GEMM (one-shot) ----------------
__global__ __launch_bounds__(256) void k_pm(
  const float* __restrict__ memory, const float* __restrict__ mw, float* __restrict__ pm)
{
  int row = blockIdx.x*2 + (threadIdx.x>>7);
  int col = threadIdx.x & 127;
  const float* mr = memory + (size_t)row*512;
  const float* wr = mw + (size_t)col*512;
  float acc=0.f;
  for (int k=0;k<512;k+=4){
    float4 a=*(const float4*)(mr+k), b=*(const float4*)(wr+k);
    acc += a.x*b.x + a.y*b.y + a.z*b.z + a.w*b.w;
  }
  pm[(size_t)row*128+col]=acc;
}

// ---------------- persistent cooperative decoder ----------------
struct PArgs {
  const float* awih; const float* awhh; const float* abih; const float* abhh;
  const float* dwih; const float* dwhh; const float* dbih; const float* dbhh;
  const float* lcw;  const float* llw;  const float* vw;
  const float* pjb;  const float* gb;
  const float* pm;   const int* mlen;
  const ushortT* preo; const ushortT* Wq; const ushortT* Wpg; const ushortT* Mbf;
  ushortT* AH0; ushortT* AH1; ushortT* DH0; ushortT* DH1; ushortT* CT0; ushortT* CT1;
  float* aw; float* awc; float* ebuf;
  float* out_mel; float* out_gate; float* out_align;
  uint32_t* bars;
  uint32_t katt_a, katt_b, kdec_a, kdec_b;
};

// Hierarchical grid barrier (r8-proven): 8 group lines + master, monotonic.
// Release fence on arrival flushes plain stores to LLC; NO acquire fence —
// cross-block mutable data is read with sc1-bypass atomic loads.
// r13: spin nap 2 -> 1 (64-cycle poll quantum) for faster wakeup.
__device__ __forceinline__ void gridbar(uint32_t* bars, uint32_t* myg){
  __syncthreads();
  if (threadIdx.x == 0){
    uint32_t g = *myg + 1u; *myg = g;
    __builtin_amdgcn_fence(__ATOMIC_RELEASE, "agent");
    uint32_t* gc  = bars + 32u*(blockIdx.x & 7u);
    uint32_t* mc  = bars + 256u;
    uint32_t* gen = bars + 288u;
    uint32_t prev = __hip_atomic_fetch_add(gc,1u,__ATOMIC_RELAXED,__HIP_MEMORY_SCOPE_AGENT);
    bool setter=false;
    if (prev == g*32u - 1u){
      uint32_t p2 = __hip_atomic_fetch_add(mc,1u,__ATOMIC_RELAXED,__HIP_MEMORY_SCOPE_AGENT);
      if (p2 == g*8u - 1u){
        __hip_atomic_store(gen, g, __ATOMIC_RELAXED, __HIP_MEMORY_SCOPE_AGENT);
        setter=true;
      }
    }
    if (!setter){
      while (__hip_atomic_load(gen, __ATOMIC_RELAXED, __HIP_MEMORY_SCOPE_AGENT) < g){
        __builtin_amdgcn_s_sleep(1);
      }
    }
  }
  __syncthreads();
}

__global__ __launch_bounds__(256,1) void k_persist(PArgs p){
  // LDS bytes: Wa 57600 + Wd 82176 + gbufA 4224 + gbufD 4224 + acst 512 + dcst 512
  //          + biasA 64 + biasD 64 + sc 13600  = 162,976  (<= 163,840)
  __shared__ ushortT Wa[16*1800];       // att rows: [preo 0..255 | ctx 256..767 | ah 768..1791]
  __shared__ ushortT Wd[16*2568];       // dec rows: [ah 0..1023 | ctx 1024..1535 | dh 1536..2559]
  __shared__ float gbufA[2][16][33];    // P1: att gate partials; P2: xA; P3: pv+red
  __shared__ float gbufD[2][16][33];    // P1: dec gate partials; P2: xD
  __shared__ float acst[4][32];
  __shared__ float dcst[4][32];
  __shared__ float biasA[16];
  __shared__ float biasD[16];
  __shared__ float sc[3400];            // P2: locl[3200]; P2-proj: [0..1023]; P3: ctx partials[256]

  const int tid = threadIdx.x;
  const int bid = blockIdx.x;
  const int lane = tid & 63;
  const int wv = tid >> 6;
  const int quad = lane >> 4;
  const int nl = lane & 15;
  const int mt = wv & 1;       // batch half
  const int kh = wv >> 1;      // K half

  // ---- one-time init: weights fp32 -> bf16 LDS, states ----
  for (int rl=0; rl<16; ++rl){
    const int r = (rl>>2)*1024 + bid*4 + (rl&3);   // gate-major rows, 4 units/block
    for (int c=tid; c<1792; c+=256){
      float v = (c<768) ? p.awih[(size_t)r*768+c] : p.awhh[(size_t)r*1024+(c-768)];
      Wa[rl*1800+c] = f2bf(v);
    }
    for (int c=tid; c<2560; c+=256){
      float v = (c<1536) ? p.dwih[(size_t)r*1536+c] : p.dwhh[(size_t)r*1024+(c-1536)];
      Wd[rl*2568+c] = f2bf(v);
    }
  }
  if (tid < 16){
    int g=tid>>2, u=bid*4+(tid&3);
    biasA[tid]=p.abih[g*1024+u]+p.abhh[g*1024+u];
    biasD[tid]=p.dbih[g*1024+u]+p.dbhh[g*1024+u];
  }
  if (tid < 128){ acst[tid>>5][tid&31]=0.f; dcst[tid>>5][tid&31]=0.f; }
  __syncthreads();

  uint32_t myg = 0;

  for (int t=0; t<=TOUT; ++t){
    const ushortT* AHp = (t&1)? p.AH0 : p.AH1;   // AH(t-1)
    ushortT*       AHn = (t&1)? p.AH1 : p.AH0;   // AH(t)
    const ushortT* DHi = (t&1)? p.DH1 : p.DH0;   // DH(t-2)
    ushortT*       DHo = (t&1)? p.DH0 : p.DH1;   // DH(t-1)
    const ushortT* CTXp= (t&1)? p.CT1 : p.CT0;   // ctx(t-1)
    ushortT*       CTXn= (t&1)? p.CT0 : p.CT1;   // ctx(t)

    // ================= P1: att-LSTM(t) || dec-LSTM(t-1) =================
    // sc1 loads 4-wide-batched, adjacent to uses (r8-proven pattern).
    const int arow = mt*16 + nl;   // batch row for A fragments
    if (t < TOUT){
      const ushortT* Xp = p.preo + ((size_t)t*32 + arow)*256 + quad*8;
      const ushortT* Xc = CTXp + arow*512 + quad*8;
      const ushortT* Xa = AHp + arow*1024 + quad*8;
      const ushortT* wr = Wa + nl*1800 + quad*8;
      f4v acc = {0.f,0.f,0.f,0.f};
      if (kh==0){
        #pragma unroll
        for (int kb=0;kb<8;++kb)  acc = mfma16(*(const s8v*)(Xp+kb*32), *(const s8v*)(wr+kb*32), acc);
        #pragma unroll
        for (int kb=0;kb<16;kb+=4){
          s8v x0=ld8_sc1(Xc+kb*32), x1=ld8_sc1(Xc+(kb+1)*32), x2=ld8_sc1(Xc+(kb+2)*32), x3=ld8_sc1(Xc+(kb+3)*32);
          acc = mfma16(x0, *(const s8v*)(wr+256+kb*32), acc);
          acc = mfma16(x1, *(const s8v*)(wr+256+(kb+1)*32), acc);
          acc = mfma16(x2, *(const s8v*)(wr+256+(kb+2)*32), acc);
          acc = mfma16(x3, *(const s8v*)(wr+256+(kb+3)*32), acc);
        }
        #pragma unroll
        for (int kb=0;kb<4;++kb)  acc = mfma16(ld8_sc1(Xa+kb*32), *(const s8v*)(wr+768+kb*32), acc);
      } else {
        #pragma unroll
        for (int kb=0;kb<28;kb+=4){
          s8v x0=ld8_sc1(Xa+128+kb*32), x1=ld8_sc1(Xa+128+(kb+1)*32), x2=ld8_sc1(Xa+128+(kb+2)*32), x3=ld8_sc1(Xa+128+(kb+3)*32);
          acc = mfma16(x0, *(const s8v*)(wr+896+kb*32), acc);
          acc = mfma16(x1, *(const s8v*)(wr+896+(kb+1)*32), acc);
          acc = mfma16(x2, *(const s8v*)(wr+896+(kb+2)*32), acc);
          acc = mfma16(x3, *(const s8v*)(wr+896+(kb+3)*32), acc);
        }
      }
      #pragma unroll
      for (int r4=0;r4<4;++r4) gbufA[kh][nl][mt*16+quad*4+r4]=acc[r4];
    }
    if (t >= 1){
      const ushortT* Xa = AHp + arow*1024 + quad*8;
      const ushortT* Xc = CTXp + arow*512 + quad*8;
      const ushortT* Xd = DHi + arow*1024 + quad*8;
      const ushortT* wr = Wd + nl*2568 + quad*8;
      f4v acc = {0.f,0.f,0.f,0.f};
      if (kh==0){
        #pragma unroll
        for (int kb=0;kb<32;kb+=4){
          s8v x0=ld8_sc1(Xa+kb*32), x1=ld8_sc1(Xa+(kb+1)*32), x2=ld8_sc1(Xa+(kb+2)*32), x3=ld8_sc1(Xa+(kb+3)*32);
          acc = mfma16(x0, *(const s8v*)(wr+kb*32), acc);
          acc = mfma16(x1, *(const s8v*)(wr+(kb+1)*32), acc);
          acc = mfma16(x2, *(const s8v*)(wr+(kb+2)*32), acc);
          acc = mfma16(x3, *(const s8v*)(wr+(kb+3)*32), acc);
        }
        #pragma unroll
        for (int kb=0;kb<8;kb+=4){
          s8v x0=ld8_sc1(Xc+kb*32), x1=ld8_sc1(Xc+(kb+1)*32), x2=ld8_sc1(Xc+(kb+2)*32), x3=ld8_sc1(Xc+(kb+3)*32);
          acc = mfma16(x0, *(const s8v*)(wr+1024+kb*32), acc);
          acc = mfma16(x1, *(const s8v*)(wr+1024+(kb+1)*32), acc);
          acc = mfma16(x2, *(const s8v*)(wr+1024+(kb+2)*32), acc);
          acc = mfma16(x3, *(const s8v*)(wr+1024+(kb+3)*32), acc);
        }
      } else {
        #pragma unroll
        for (int kb=0;kb<8;kb+=4){
          s8v x0=ld8_sc1(Xc+256+kb*32), x1=ld8_sc1(Xc+256+(kb+1)*32), x2=ld8_sc1(Xc+256+(kb+2)*32), x3=ld8_sc1(Xc+256+(kb+3)*32);
          acc = mfma16(x0, *(const s8v*)(wr+1280+kb*32), acc);
          acc = mfma16(x1, *(const s8v*)(wr+1280+(kb+1)*32), acc);
          acc = mfma16(x2, *(const s8v*)(wr+1280+(kb+2)*32), acc);
          acc = mfma16(x3, *(const s8v*)(wr+1280+(kb+3)*32), acc);
        }
        #pragma unroll
        for (int kb=0;kb<32;kb+=4){
          s8v x0=ld8_sc1(Xd+kb*32), x1=ld8_sc1(Xd+(kb+1)*32), x2=ld8_sc1(Xd+(kb+2)*32), x3=ld8_sc1(Xd+(kb+3)*32);
          acc = mfma16(x0, *(const s8v*)(wr+1536+kb*32), acc);
          acc = mfma16(x1, *(const s8v*)(wr+1536+(kb+1)*32), acc);
          acc = mfma16(x2, *(const s8v*)(wr+1536+(kb+2)*32), acc);
          acc = mfma16(x3, *(const s8v*)(wr+1536+(kb+3)*32), acc);
        }
      }
      #pragma unroll
      for (int r4=0;r4<4;++r4) gbufD[kh][nl][mt*16+quad*4+r4]=acc[r4];
    }
    __syncthreads();
    if (t < TOUT && tid < 128){
      const int uu=tid>>5, b=tid&31, u=bid*4+uu;
      float gi=gbufA[0][uu][b]   +gbufA[1][uu][b]   +biasA[uu];
      float gf=gbufA[0][4+uu][b] +gbufA[1][4+uu][b] +biasA[4+uu];
      float gg=gbufA[0][8+uu][b] +gbufA[1][8+uu][b] +biasA[8+uu];
      float go=gbufA[0][12+uu][b]+gbufA[1][12+uu][b]+biasA[12+uu];
      float cp=acst[uu][b];
      float c2=sigm(gf)*cp+sigm(gi)*tanhf(gg);
      float h =sigm(go)*tanhf(c2);
      uint32_t fidx=((uint32_t)(t*32+b))*1024u+(uint32_t)u;
      h=(part_unif(p.katt_a,p.katt_b,fidx)<0.9f)? h*(1.0f/0.9f):0.f;
      acst[uu][b]=c2;
      AHn[b*1024+u]=f2bf(h);
    }
    if (t >= 1 && tid >= 128){
      const int uu=(tid>>5)&3, b=tid&31, u=bid*4+uu;
      float gi=gbufD[0][uu][b]   +gbufD[1][uu][b]   +biasD[uu];
      float gf=gbufD[0][4+uu][b] +gbufD[1][4+uu][b] +biasD[4+uu];
      float gg=gbufD[0][8+uu][b] +gbufD[1][8+uu][b] +biasD[8+uu];
      float go=gbufD[0][12+uu][b]+gbufD[1][12+uu][b]+biasD[12+uu];
      float cp=dcst[uu][b];
      float c2=sigm(gf)*cp+sigm(gi)*tanhf(gg);
      float h =sigm(go)*tanhf(c2);
      uint32_t fidx=((uint32_t)((t-1)*32+b))*1024u+(uint32_t)u;
      h=(part_unif(p.kdec_a,p.kdec_b,fidx)<0.9f)? h*(1.0f/0.9f):0.f;
      dcst[uu][b]=c2;
      DHo[b*1024+u]=f2bf(h);
    }
    gridbar(p.bars,&myg);

    // ================= P2: attention energies (blocks 0..127 = b x 100-pos chunk)
    //                      || projection(t-1) (blocks 128..133) =================
    if (bid < 128){
      if (t < TOUT){
        const int b = bid>>2, ch = bid&3, t0 = ch*100;
        float* xA = (float*)gbufA;          // [0..511] sAH(ushort x1024), [512..767] pq2, [768..895] pqs
        float* xD = (float*)gbufD;          // [0..129] awp, [130..259] awcp, [260..459] epart
        ushortT* sAH = (ushortT*)xA;
        // stage ah(t) via sc1 (mutable) + halo of aw/awc(t-1) via sc1
        {
          const uint32_t* ahsrc = (const uint32_t*)(AHn + b*1024);
          for (int i=tid;i<512;i+=256) ((uint32_t*)sAH)[i] = ld32_sc1(ahsrc + i);
        }
        for (int i=tid;i<130;i+=256){
          int tt=t0-15+i; float a_=0.f,c_=0.f;
          if (tt>=0 && tt<TIN){ a_=ldf_sc1(p.aw + b*TIN+tt); c_=ldf_sc1(p.awc + b*TIN+tt); }
          xD[i]=a_; xD[130+i]=c_;
        }
        __syncthreads();
        { // pq = query_w @ ah (bf16 x bf16, fp32 accum)  [r5-proven]
          const int a=tid&127, half=tid>>7;
          const ushortT* qr = p.Wq + a*1024 + half*512;
          const ushortT* hr = sAH + half*512;
          float acc=0.f;
          for (int k=0;k<512;k+=8){
            s8v q=*(const s8v*)(qr+k);
            s8v h=*(const s8v*)(hr+k);
            #pragma unroll
            for (int j=0;j<8;++j) acc += bf2f((ushortT)q[j])*bf2f((ushortT)h[j]);
          }
          xA[512+tid]=acc;
        }
        // conv -> locl[tl*32+f], tl in [0,100)  [r0-B1 geometry, direct-global lcw]
        for (int it=tid; it<3200; it+=256){
          const int tl=it>>5, f=it&31;
          const float* c0p=p.lcw + (f*2)*31;
          const float* c1p=c0p + 31;
          float s=0.f;
          #pragma unroll
          for (int j=0;j<31;++j) s += xD[tl+j]*c0p[j] + xD[130+tl+j]*c1p[j];
          sc[tl*32+f]=s;
        }
        __syncthreads();
        if (tid<128) xA[768+tid]=xA[512+tid]+xA[512+128+tid];
        __syncthreads();
        // energies [r0-B1 per-wave reduce], exp [r2/r5-proven no-max]
        {
          const int a_=tid&127, g=tid>>7, wid=tid>>6;
          float lw_r[32];
          #pragma unroll
          for (int j=0;j<32;++j) lw_r[j]=p.llw[a_*32+j];
          const float vr = p.vw[a_];
          const float pqa = xA[768+a_];
          for (int tl=g; tl<100; tl+=2){
            const float* lt = sc + tl*32;
            float l2=0.f;
            #pragma unroll
            for (int f=0;f<32;++f) l2 += lt[f]*lw_r[f];
            float x = pqa + l2 + p.pm[((size_t)b*TIN + (t0+tl))*128 + a_];
            x = fminf(fmaxf(x,-30.f),30.f);
            float ex = __expf(2.f*x);
            float cv = vr*((ex-1.f)*__builtin_amdgcn_rcpf(ex+1.f));
            #pragma unroll
            for (int o=32;o>0;o>>=1) cv += __shfl_xor(cv,o);
            if ((tid&63)==0) xD[260 + tl*2 + (wid&1)]=cv;
          }
        }
        __syncthreads();
        if (tid<100){
          const int tg=t0+tid;
          float e = xD[260+tid*2] + xD[260+tid*2+1];
          float pv = (tg < p.mlen[b]) ? __expf(e) : 0.f;
          p.ebuf[b*TIN+tg]=pv;
        }
      }
    } else if (bid < 134){
      if (t >= 1){
        const int td=t-1, rb=(bid-128)*16;
        const int mrow = nl + mt*16;
        const ushortT* br  = p.Wpg + (size_t)(rb+nl)*1536 + quad*8;
        const ushortT* dhp = DHo + (size_t)mrow*1024 + quad*8;
        const ushortT* cxp = CTXp + (size_t)mrow*512 + quad*8;
        f4v acc={0.f,0.f,0.f,0.f};
        for (int kb=0;kb<24;++kb){
          const int kk=kh*768+kb*32;
          s8v aa = (kk<1024)? ld8_sc1(dhp+kk) : ld8_sc1(cxp+(kk-1024));
          acc = mfma16(aa, *(const s8v*)(br+kk), acc);
        }
        #pragma unroll
        for (int r4=0;r4<4;++r4) sc[kh*512 + (mt*16+quad*4+r4)*16 + nl]=acc[r4];
        __syncthreads();
        for (int idx=tid; idx<512; idx+=256){
          const int m=idx>>4, n=idx&15, r=rb+n;
          float v=sc[m*16+n]+sc[512+m*16+n];
          if (r<80) p.out_mel[(size_t)(m*80+r)*500+td]=v+p.pjb[r];
          else if (r==80) p.out_gate[(size_t)m*500+td]=v+p.gb[0];
        }
      }
    }
    gridbar(p.bars,&myg);

    // ================= P3: normalize + context, all 256 blocks (b=bid>>3, s=bid&7) =========
    if (t < TOUT){
      const int b = bid>>3, s = bid&7;
      float* pv  = (float*)gbufA;     // [0..399]
      float* red = pv + 408;          // [408..411]
      for (int i=tid;i<TIN;i+=256) pv[i]=ldf_sc1(p.ebuf + b*TIN + i);
      __syncthreads();
      float ls=0.f;
      for (int i=tid;i<TIN;i+=256) ls+=pv[i];
      #pragma unroll
      for (int o=32;o>0;o>>=1) ls+=__shfl_xor(ls,o);
      if ((tid&63)==0) red[tid>>6]=ls;
      __syncthreads();
      const float S=red[0]+red[1]+red[2]+red[3];
      const float rS=(S>0.f)?1.0f/S:0.f;
      // context slice: dims [s*64, s*64+64), quarters of positions
      const int dl = tid&63, q = tid>>6;
      const int d = s*64 + dl;
      const ushortT* mb = p.Mbf + ((size_t)b*TIN + q*100)*512 + d;
      const float* pq_ = pv + q*100;
      float cc=0.f;
      #pragma unroll 4
      for (int tt=0;tt<100;++tt) cc += pq_[tt]*bf2f(mb[(size_t)tt*512]);
      sc[q*64+dl]=cc;
      __syncthreads();
      if (q==0){
        float v = sc[dl]+sc[64+dl]+sc[128+dl]+sc[192+dl];
        CTXn[b*512+d]=f2bf(v*rS);
      }
      if (s==0){
        for (int i=tid;i<TIN;i+=256){
          float a2 = pv[i]*rS;
          p.aw[b*TIN+i]=a2;
          p.awc[b*TIN+i]+=a2;
          p.out_align[((size_t)b*500+t)*400+i]=a2;
        }
      }
    }
    gridbar(p.bars,&myg);
  }
}

// ---------------- host ----------------
extern "C" void kernel_launch(void* const* d_in, const int* in_sizes, int n_in,
                              void* d_out, int out_size, void* d_ws, size_t ws_size,
                              hipStream_t stream) {
  (void)in_sizes; (void)n_in; (void)out_size; (void)ws_size;
  const float* memory  = (const float*)d_in[0];
  const float* dec_inp = (const float*)d_in[1];
  const int*   mlen    = (const int*)d_in[2];
  const float* pw1     = (const float*)d_in[3];
  const float* pw2     = (const float*)d_in[4];
  const float* awih    = (const float*)d_in[5];
  const float* awhh    = (const float*)d_in[6];
  const float* abih    = (const float*)d_in[7];
  const float* abhh    = (const float*)d_in[8];
  const float* qw      = (const float*)d_in[9];
  const float* mw      = (const float*)d_in[10];
  const float* vw      = (const float*)d_in[11];
  const float* lcw     = (const float*)d_in[12];
  const float* llw     = (const float*)d_in[13];
  const float* dwih    = (const float*)d_in[14];
  const float* dwhh    = (const float*)d_in[15];
  const float* dbih    = (const float*)d_in[16];
  const float* dbhh    = (const float*)d_in[17];
  const float* pjw     = (const float*)d_in[18];
  const float* pjb     = (const float*)d_in[19];
  const float* gw      = (const float*)d_in[20];
  const float* gb      = (const float*)d_in[21];

  char* w = (char*)d_ws;
  size_t off=0;
  auto alloc = [&](size_t n)->char*{ char* p=w+off; off=(off+n+255)&~(size_t)255; return p; };
  ushortT* Mbf = (ushortT*)alloc(32UL*400*512*2);
  ushortT* Wq  = (ushortT*)alloc(128UL*1024*2);
  ushortT* Wpg = (ushortT*)alloc(96UL*1536*2);
  ushortT* preo= (ushortT*)alloc(16000UL*256*2);
  float*   pm  = (float*)alloc(12800UL*128*4);
  ushortT* AH0 = (ushortT*)alloc(32UL*1024*2);
  ushortT* AH1 = (ushortT*)alloc(32UL*1024*2);
  ushortT* DH0 = (ushortT*)alloc(32UL*1024*2);
  ushortT* DH1 = (ushortT*)alloc(32UL*1024*2);
  ushortT* CT0 = (ushortT*)alloc(32UL*512*2);
  ushortT* CT1 = (ushortT*)alloc(32UL*512*2);
  float*   aw  = (float*)alloc(12800UL*4);
  float*   awc = (float*)alloc(12800UL*4);
  float*   ebuf= (float*)alloc(12800UL*4);
  uint32_t* bars=(uint32_t*)alloc(2048);

  // JAX partitionable split(key(42), 4)
  uint32_t K[4][2];
  for (uint32_t i=0;i<4;++i) tf2x32(0u,42u,0u,i,&K[i][0],&K[i][1]);

  float* out_mel   = (float*)d_out;
  float* out_gate  = out_mel + 1280000;
  float* out_align = out_mel + 1296000;

  k_setup<<<1024,256,0,stream>>>(memory,qw,pjw,gw,Mbf,Wq,Wpg,AH0,AH1,DH0,DH1,CT0,CT1,aw,awc,bars);
  k_prenet<<<250,256,0,stream>>>(dec_inp, pw1, pw2, preo, K[0][0],K[0][1], K[1][0],K[1][1]);
  k_pm<<<6400,256,0,stream>>>(memory, mw, pm);

  PArgs pa;
  pa.awih=awih; pa.awhh=awhh; pa.abih=abih; pa.abhh=abhh;
  pa.dwih=dwih; pa.dwhh=dwhh; pa.dbih=dbih; pa.dbhh=dbhh;
  pa.lcw=lcw; pa.llw=llw; pa.vw=vw; pa.pjb=pjb; pa.gb=gb;
  pa.pm=pm; pa.mlen=mlen;
  pa.preo=preo; pa.Wq=Wq; pa.Wpg=Wpg; pa.Mbf=Mbf;
  pa.AH0=AH0; pa.AH1=AH1; pa.DH0=DH0; pa.DH1=DH1; pa.CT0=CT0; pa.CT1=CT1;
  pa.aw=aw; pa.awc=awc; pa.ebuf=ebuf;
  pa.out_mel=out_mel; pa.out_gate=out_gate; pa.out_align=out_align;
  pa.bars=bars;
  pa.katt_a=K[2][0]; pa.katt_b=K[2][1]; pa.kdec_a=K[3][0]; pa.kdec_b=K[3][1];

  void* kargs[] = { &pa };
  (void)hipLaunchCooperativeKernel((const void*)k_persist, dim3(256), dim3(256), kargs, 0u, stream);
}